// Round 2
// baseline (1514.156 us; speedup 1.0000x reference)
//
#include <hip/hip_runtime.h>

// GAT 2-layer forward on MI355X.
// Round 1: replace scatter fill (197MB write traffic, 280us) with bucketed
// two-pass counting sort:
//   pass1: scatter packed (src,dst&127) into dst-bucket regions carved from
//          the final CSR layout (bucket = dst>>7) -> near-1x write amp.
//   pass2: one WG per bucket, LDS cursors, contiguous-window csr writes.
// hist now reads only the dst row (half the bytes).

#define DEVFN __device__ __forceinline__
#define BKT_BITS 7
#define BKT_SZ 128

// ---------------- edge dtype detection (int64 vs int32) ----------------
__global__ void detect_kernel(const int* eg32, int E, int* flag) {
  __shared__ int any;
  if (threadIdx.x == 0) any = 0;
  __syncthreads();
  for (int k = threadIdx.x; k < 2048 && k < E; k += 256) {
    if (eg32[2 * k + 1] != 0) atomicOr(&any, 1);
  }
  __syncthreads();
  if (threadIdx.x == 0) flag[0] = any ? 0 : 1;  // 1 => int64
}

// ---------------- CSR build ----------------
__global__ void zero_int(int* p, int n) {
  int i = blockIdx.x * 256 + threadIdx.x;
  if (i < n) p[i] = 0;
}

// histogram of dst (reads only the dst row)
__global__ void hist_kernel(const long long* eg64, const int* eg32, const int* flag,
                            int E, int N, int* cnt) {
  int i = blockIdx.x * 256 + threadIdx.x;
  int EN = E + N;
  if (i >= EN) return;
  int d;
  if (i >= E) d = i - E;
  else if (flag[0]) d = (int)eg64[E + i];
  else d = eg32[E + i];
  atomicAdd(&cnt[d], 1);
}

__global__ void scan_blocks(const int* __restrict__ cnt, int* __restrict__ rp,
                            int* __restrict__ bsum, int n) {
  __shared__ int buf[2][1024];
  int t = threadIdx.x;
  int gid = blockIdx.x * 1024 + t;
  int v = (gid < n) ? cnt[gid] : 0;
  buf[0][t] = v;
  __syncthreads();
  int pin = 0;
  for (int offd = 1; offd < 1024; offd <<= 1) {
    int nv = buf[pin][t];
    if (t >= offd) nv += buf[pin][t - offd];
    buf[1 - pin][t] = nv;
    pin = 1 - pin;
    __syncthreads();
  }
  int inc = buf[pin][t];
  if (gid < n) rp[gid] = inc - v;  // exclusive within block
  if (t == 1023) bsum[blockIdx.x] = inc;
}

__global__ void scan_sums(const int* bsum, int* boff, int nb) {
  if (blockIdx.x == 0 && threadIdx.x == 0) {
    int r = 0;
    for (int i = 0; i < nb; i++) { boff[i] = r; r += bsum[i]; }
  }
}

__global__ void scan_add(int* rp, const int* boff, int n, int total) {
  int i = blockIdx.x * 1024 + threadIdx.x;
  if (i < n) rp[i] = rp[i] + boff[blockIdx.x];
  if (i == 0) rp[n] = total;
}

// per-bucket cursor init: bcur[b] = rp[min(b*BKT_SZ, N)]
__global__ void bcur_init(const int* __restrict__ rp, int* __restrict__ bcur,
                          int nbk, int N) {
  int b = blockIdx.x * 256 + threadIdx.x;
  if (b >= nbk) return;
  int n0 = b * BKT_SZ;
  bcur[b] = rp[n0 > N ? N : n0];
}

// pass1: scatter packed (src<<7 | dst&127) into bucket regions
__global__ void bucket_scatter(const long long* eg64, const int* eg32,
                               const int* flag, int E, int N,
                               int* __restrict__ bcur, int* __restrict__ tmp) {
  int i = blockIdx.x * 256 + threadIdx.x;
  int EN = E + N;
  if (i >= EN) return;
  int s, d;
  if (i >= E) { s = d = i - E; }
  else if (flag[0]) { s = (int)eg64[i]; d = (int)eg64[E + i]; }
  else { s = eg32[i]; d = eg32[E + i]; }
  int b = d >> BKT_BITS;
  int pos = atomicAdd(&bcur[b], 1);
  tmp[pos] = (s << BKT_BITS) | (d & (BKT_SZ - 1));
}

// pass2: one WG per bucket; LDS cursors -> contiguous-window csr writes
__global__ __launch_bounds__(256) void bucket_sort(const int* __restrict__ rp,
                                                   const int* __restrict__ tmp,
                                                   int* __restrict__ csr, int N) {
  __shared__ int lcur[BKT_SZ];
  int b = blockIdx.x;
  int n0 = b * BKT_SZ;
  int n1 = n0 + BKT_SZ; if (n1 > N) n1 = N;
  int t = threadIdx.x;
  if (t < n1 - n0) lcur[t] = rp[n0 + t];
  __syncthreads();
  int seg0 = rp[n0], seg1 = rp[n1];
  for (int p = seg0 + t; p < seg1; p += 256) {
    int e = tmp[p];
    int dl = e & (BKT_SZ - 1);
    int s = e >> BKT_BITS;
    int pos = atomicAdd(&lcur[dl], 1);
    csr[pos] = s;
  }
}

// ---------------- dense GEMMs ----------------
// h1[N,32] = X[N,128] @ W1[128,32]; thread = (row, 4 consecutive out channels)
__global__ __launch_bounds__(256) void gemm1_kernel(const float* __restrict__ X,
                                                    const float* __restrict__ W,
                                                    float* __restrict__ h1, int N) {
  __shared__ float Wl[128 * 32];
  int t = threadIdx.x;
  for (int i = t; i < 128 * 32 / 4; i += 256)
    ((float4*)Wl)[i] = ((const float4*)W)[i];
  __syncthreads();
  int idx = blockIdx.x * 256 + t;  // over N*8
  if (idx >= N * 8) return;
  int n = idx >> 3, cq = idx & 7;
  const float4* X4 = (const float4*)(X + (size_t)n * 128);
  float4 acc = make_float4(0.f, 0.f, 0.f, 0.f);
#pragma unroll
  for (int k4 = 0; k4 < 32; k4++) {
    float4 x = X4[k4];
    const float4* wr = (const float4*)(Wl + (k4 * 4) * 32 + cq * 4);
    float4 w0 = wr[0], w1 = wr[8], w2 = wr[16], w3 = wr[24];
    acc.x = fmaf(x.x, w0.x, acc.x); acc.y = fmaf(x.x, w0.y, acc.y);
    acc.z = fmaf(x.x, w0.z, acc.z); acc.w = fmaf(x.x, w0.w, acc.w);
    acc.x = fmaf(x.y, w1.x, acc.x); acc.y = fmaf(x.y, w1.y, acc.y);
    acc.z = fmaf(x.y, w1.z, acc.z); acc.w = fmaf(x.y, w1.w, acc.w);
    acc.x = fmaf(x.z, w2.x, acc.x); acc.y = fmaf(x.z, w2.y, acc.y);
    acc.z = fmaf(x.z, w2.z, acc.z); acc.w = fmaf(x.z, w2.w, acc.w);
    acc.x = fmaf(x.w, w3.x, acc.x); acc.y = fmaf(x.w, w3.y, acc.y);
    acc.z = fmaf(x.w, w3.z, acc.z); acc.w = fmaf(x.w, w3.w, acc.w);
  }
  ((float4*)h1)[idx] = acc;
}

// h2[N,40] = x1[N,32] @ W2[32,40]; thread = (row, 4 consecutive out channels)
__global__ __launch_bounds__(256) void gemm2_kernel(const float* __restrict__ X,
                                                    const float* __restrict__ W,
                                                    float* __restrict__ h2, int N) {
  __shared__ float Wl[32 * 40];
  int t = threadIdx.x;
  for (int i = t; i < 32 * 40 / 4; i += 256)
    ((float4*)Wl)[i] = ((const float4*)W)[i];
  __syncthreads();
  int idx = blockIdx.x * 256 + t;  // over N*10
  if (idx >= N * 10) return;
  int n = idx / 10, cq = idx % 10;
  const float4* X4 = (const float4*)(X + (size_t)n * 32);
  float4 acc = make_float4(0.f, 0.f, 0.f, 0.f);
#pragma unroll
  for (int k4 = 0; k4 < 8; k4++) {
    float4 x = X4[k4];
    const float4* wr = (const float4*)(Wl + (k4 * 4) * 40 + cq * 4);
    float4 w0 = wr[0], w1 = wr[10], w2 = wr[20], w3 = wr[30];
    acc.x = fmaf(x.x, w0.x, acc.x); acc.y = fmaf(x.x, w0.y, acc.y);
    acc.z = fmaf(x.x, w0.z, acc.z); acc.w = fmaf(x.x, w0.w, acc.w);
    acc.x = fmaf(x.y, w1.x, acc.x); acc.y = fmaf(x.y, w1.y, acc.y);
    acc.z = fmaf(x.y, w1.z, acc.z); acc.w = fmaf(x.y, w1.w, acc.w);
    acc.x = fmaf(x.z, w2.x, acc.x); acc.y = fmaf(x.z, w2.y, acc.y);
    acc.z = fmaf(x.z, w2.z, acc.z); acc.w = fmaf(x.z, w2.w, acc.w);
    acc.x = fmaf(x.w, w3.x, acc.x); acc.y = fmaf(x.w, w3.y, acc.y);
    acc.z = fmaf(x.w, w3.z, acc.z); acc.w = fmaf(x.w, w3.w, acc.w);
  }
  ((float4*)h2)[idx] = acc;
}

// ---------------- attention scalar projections ----------------
template <int H, int C>
__global__ __launch_bounds__(256) void attn_kernel(const float* __restrict__ h,
                                                   const float* __restrict__ att_s,
                                                   const float* __restrict__ att_d,
                                                   float* __restrict__ as,
                                                   float* __restrict__ ad, int N) {
  int n = blockIdx.x * 256 + threadIdx.x;
  if (n >= N) return;
  const float* hr = h + (size_t)n * (H * C);
#pragma unroll
  for (int hh = 0; hh < H; hh++) {
    float ss = 0.f, sd = 0.f;
#pragma unroll
    for (int c = 0; c < C; c++) {
      float v = hr[hh * C + c];
      ss = fmaf(v, att_s[hh * C + c], ss);
      sd = fmaf(v, att_d[hh * C + c], sd);
    }
    as[n * H + hh] = ss;
    ad[n * H + hh] = sd;
  }
}

// ---------------- segment softmax (two-pass, stores exp(e-m)) ----------------
template <int H>
__global__ __launch_bounds__(256) void softmax_kernel(const int* __restrict__ rp,
                                                      const int* __restrict__ csr,
                                                      const float* __restrict__ as,
                                                      const float* __restrict__ ad,
                                                      float* __restrict__ alpha,
                                                      float* __restrict__ ssum, int N) {
  int t = blockIdx.x * 256 + threadIdx.x;
  if (t >= N * H) return;
  int n = t / H, h = t % H;
  int p0 = rp[n], p1 = rp[n + 1];
  float adv = ad[n * H + h];
  float m = -1e30f;
  for (int p = p0; p < p1; p++) {
    int s = csr[p];
    float e = as[s * H + h] + adv;
    e = e > 0.f ? e : 0.2f * e;
    m = fmaxf(m, e);
  }
  float sum = 0.f;
  for (int p = p0; p < p1; p++) {
    int s = csr[p];
    float e = as[s * H + h] + adv;
    e = e > 0.f ? e : 0.2f * e;
    float ex = __expf(e - m);
    sum += ex;
    alpha[p * H + h] = ex;
  }
  ssum[n * H + h] = sum;
}

// ---------------- aggregation: thread = (node, float4 of channels) ----------------
template <int H, int C, bool RELU>
__global__ __launch_bounds__(256) void agg_kernel(const int* __restrict__ rp,
                                                  const int* __restrict__ csr,
                                                  const float* __restrict__ alpha,
                                                  const float* __restrict__ ssum,
                                                  const float* __restrict__ hfeat,
                                                  const float* __restrict__ bias,
                                                  float* __restrict__ outp, int N) {
  constexpr int HC = H * C;
  constexpr int QV = HC / 4;
  int idx = blockIdx.x * 256 + threadIdx.x;  // over N*QV
  if (idx >= N * QV) return;
  int n = idx / QV, cq = idx % QV;
  int h = (cq * 4) / C;
  int p0 = rp[n], p1 = rp[n + 1];
  const float4* hf4 = (const float4*)hfeat;
  float4 acc = make_float4(0.f, 0.f, 0.f, 0.f);
  for (int p = p0; p < p1; p++) {
    int s = csr[p];
    float a = alpha[p * H + h];
    float4 v = hf4[(size_t)s * QV + cq];
    acc.x = fmaf(a, v.x, acc.x);
    acc.y = fmaf(a, v.y, acc.y);
    acc.z = fmaf(a, v.z, acc.z);
    acc.w = fmaf(a, v.w, acc.w);
  }
  float inv = 1.0f / (ssum[n * H + h] + 1e-16f);
  float4 b = ((const float4*)bias)[cq];
  float4 r;
  r.x = acc.x * inv + b.x;
  r.y = acc.y * inv + b.y;
  r.z = acc.z * inv + b.z;
  r.w = acc.w * inv + b.w;
  if (RELU) {
    r.x = fmaxf(r.x, 0.f); r.y = fmaxf(r.y, 0.f);
    r.z = fmaxf(r.z, 0.f); r.w = fmaxf(r.w, 0.f);
  }
  ((float4*)outp)[idx] = r;
}

// ---------------- host launcher ----------------
extern "C" void kernel_launch(void* const* d_in, const int* in_sizes, int n_in,
                              void* d_out, int out_size, void* d_ws, size_t ws_size,
                              hipStream_t stream) {
  const float* X    = (const float*)d_in[0];
  const long long* eg64 = (const long long*)d_in[1];
  const int* eg32   = (const int*)d_in[1];
  const float* W1   = (const float*)d_in[3];
  const float* as1w = (const float*)d_in[4];
  const float* ad1w = (const float*)d_in[5];
  const float* b1   = (const float*)d_in[6];
  const float* W2   = (const float*)d_in[7];
  const float* as2w = (const float*)d_in[8];
  const float* ad2w = (const float*)d_in[9];
  const float* b2   = (const float*)d_in[10];
  float* out = (float*)d_out;

  const int N  = in_sizes[0] / 128;
  const int E  = in_sizes[1] / 2;
  const int EN = E + N;
  const int NBK = (N + BKT_SZ - 1) / BKT_SZ;

  char* wbase = (char*)d_ws;
  size_t off = 0;
  auto alloc = [&](size_t bytes) -> void* {
    void* p = wbase + off;
    off += (bytes + 255) & ~(size_t)255;
    return p;
  };

  float* h1  = (float*)alloc((size_t)N * 32 * 4);
  float* x1  = (float*)alloc((size_t)N * 32 * 4);
  float* h2  = (float*)alloc((size_t)N * 40 * 4);
  float* as1 = (float*)alloc((size_t)N * 2 * 4);
  float* ad1 = (float*)alloc((size_t)N * 2 * 4);
  float* s1  = (float*)alloc((size_t)N * 2 * 4);
  float* as2 = (float*)alloc((size_t)N * 4);
  float* ad2 = (float*)alloc((size_t)N * 4);
  float* s2  = (float*)alloc((size_t)N * 4);
  int* cnt    = (int*)alloc((size_t)N * 4);
  int* rp     = (int*)alloc((size_t)(N + 1) * 4);
  int* bcur   = (int*)alloc((size_t)NBK * 4);
  int* bsum   = (int*)alloc(1024 * 4);
  int* boff   = (int*)alloc(1024 * 4);
  int* flag   = (int*)alloc(256);
  int* csr    = (int*)alloc((size_t)EN * 4);
  float* al1  = (float*)alloc((size_t)EN * 2 * 4);
  float* al2  = (float*)alloc((size_t)EN * 4);
  int* tmp = (int*)al1;  // alias: tmp dead before al1 is written
  (void)ws_size; (void)n_in; (void)out_size;

  const int nb  = (N + 1023) / 1024;
  const int gN  = (N + 255) / 256;
  const int gEN = (EN + 255) / 256;

  detect_kernel<<<1, 256, 0, stream>>>(eg32, E, flag);
  zero_int<<<gN, 256, 0, stream>>>(cnt, N);
  hist_kernel<<<gEN, 256, 0, stream>>>(eg64, eg32, flag, E, N, cnt);
  scan_blocks<<<nb, 1024, 0, stream>>>(cnt, rp, bsum, N);
  scan_sums<<<1, 64, 0, stream>>>(bsum, boff, nb);
  scan_add<<<nb, 1024, 0, stream>>>(rp, boff, N, EN);
  bcur_init<<<(NBK + 255) / 256, 256, 0, stream>>>(rp, bcur, NBK, N);
  bucket_scatter<<<gEN, 256, 0, stream>>>(eg64, eg32, flag, E, N, bcur, tmp);
  bucket_sort<<<NBK, 256, 0, stream>>>(rp, tmp, csr, N);

  // Layer 1
  gemm1_kernel<<<(N * 8 + 255) / 256, 256, 0, stream>>>(X, W1, h1, N);
  attn_kernel<2, 16><<<gN, 256, 0, stream>>>(h1, as1w, ad1w, as1, ad1, N);
  softmax_kernel<2><<<(N * 2 + 255) / 256, 256, 0, stream>>>(rp, csr, as1, ad1, al1, s1, N);
  agg_kernel<2, 16, true><<<(N * 8 + 255) / 256, 256, 0, stream>>>(rp, csr, al1, s1, h1, b1, x1, N);

  // Layer 2
  gemm2_kernel<<<(N * 10 + 255) / 256, 256, 0, stream>>>(x1, W2, h2, N);
  attn_kernel<1, 40><<<gN, 256, 0, stream>>>(h2, as2w, ad2w, as2, ad2, N);
  softmax_kernel<1><<<gN, 256, 0, stream>>>(rp, csr, as2, ad2, al2, s2, N);
  agg_kernel<1, 40, false><<<(N * 10 + 255) / 256, 256, 0, stream>>>(rp, csr, al2, s2, h2, b2, out, N);
}

// Round 3
// 684.731 us; speedup vs baseline: 2.2113x; 2.2113x over previous
//
#include <hip/hip_runtime.h>

// GAT 2-layer forward on MI355X.
// Round 2: atomic-free CSR build (lesson from r1/r2: global atomic cursors
// serialize across XCDs, and scatter writes must be temporally clustered to
// fill cache lines).
//   chunk_hist:   per-8192-edge WG LDS histogram of coarse buckets (dst>>9)
//   scan(histg):  bucket-major exclusive scan -> per-(bucket,WG) write bases
//   chunk_scatter: deterministic scatter of packed (src<<9|dstlocal) into
//                  contiguous ~168B runs (LDS cursors only)
//   bucket_cnt:   per-bucket LDS node counts -> cnt (replaces global-atomic hist)
//   scan(cnt)->rp; bucket_sort: LDS cursors, writes csr in 67KB L2 window
// NOTE: sized for N <= 512*512 nodes, src < 2^17 (N=100000 here).

#define DEVFN __device__ __forceinline__
#define CB_SHIFT 9
#define CB_SZ 512
#define CHUNK 8192

// ---------------- edge dtype detection (int64 vs int32) ----------------
__global__ void detect_kernel(const int* eg32, int E, int* flag) {
  __shared__ int any;
  if (threadIdx.x == 0) any = 0;
  __syncthreads();
  for (int k = threadIdx.x; k < 2048 && k < E; k += 256) {
    if (eg32[2 * k + 1] != 0) atomicOr(&any, 1);
  }
  __syncthreads();
  if (threadIdx.x == 0) flag[0] = any ? 0 : 1;  // 1 => int64
}

DEVFN int read_dst(const long long* eg64, const int* eg32, int is64, int E, int i) {
  if (i >= E) return i - E;
  return is64 ? (int)eg64[E + i] : eg32[E + i];
}

DEVFN void read_edge(const long long* eg64, const int* eg32, int is64, int E,
                     int i, int& s, int& d) {
  if (i >= E) { s = d = i - E; return; }
  if (is64) { s = (int)eg64[i]; d = (int)eg64[E + i]; }
  else      { s = eg32[i];      d = eg32[E + i]; }
}

// ---------------- generic scan (blocks of 1024) ----------------
__global__ void scan_blocks(const int* __restrict__ cnt, int* __restrict__ rp,
                            int* __restrict__ bsum, int n) {
  __shared__ int buf[2][1024];
  int t = threadIdx.x;
  int gid = blockIdx.x * 1024 + t;
  int v = (gid < n) ? cnt[gid] : 0;
  buf[0][t] = v;
  __syncthreads();
  int pin = 0;
  for (int offd = 1; offd < 1024; offd <<= 1) {
    int nv = buf[pin][t];
    if (t >= offd) nv += buf[pin][t - offd];
    buf[1 - pin][t] = nv;
    pin = 1 - pin;
    __syncthreads();
  }
  int inc = buf[pin][t];
  if (gid < n) rp[gid] = inc - v;  // exclusive within block
  if (t == 1023) bsum[blockIdx.x] = inc;
}

__global__ void scan_sums(const int* bsum, int* boff, int nb) {
  if (blockIdx.x == 0 && threadIdx.x == 0) {
    int r = 0;
    for (int i = 0; i < nb; i++) { boff[i] = r; r += bsum[i]; }
  }
}

__global__ void scan_add(int* rp, const int* boff, int n, int total) {
  int i = blockIdx.x * 1024 + threadIdx.x;
  if (i < n) rp[i] = rp[i] + boff[blockIdx.x];
  if (i == 0) rp[n] = total;
}

// ---------------- CSR build (atomic-free multisplit) ----------------
// per-chunk coarse-bucket histogram -> histg[b*NWG + w]
__global__ __launch_bounds__(256) void chunk_hist(const long long* eg64,
                                                  const int* eg32, const int* flag,
                                                  int E, int N, int NWG,
                                                  int* __restrict__ histg) {
  __shared__ int lh[CB_SZ];
  int w = blockIdx.x, t = threadIdx.x;
  int NB2 = (N + CB_SZ - 1) / CB_SZ;
  for (int j = t; j < NB2; j += 256) lh[j] = 0;
  __syncthreads();
  int is64 = flag[0];
  int EN = E + N;
  int i0 = w * CHUNK;
  int i1 = i0 + CHUNK; if (i1 > EN) i1 = EN;
  for (int i = i0 + t; i < i1; i += 256) {
    int d = read_dst(eg64, eg32, is64, E, i);
    atomicAdd(&lh[d >> CB_SHIFT], 1);
  }
  __syncthreads();
  for (int b = t; b < NB2; b += 256) histg[b * NWG + w] = lh[b];
}

// deterministic scatter using scanned per-(bucket,chunk) bases
__global__ __launch_bounds__(256) void chunk_scatter(const long long* eg64,
                                                     const int* eg32, const int* flag,
                                                     int E, int N, int NWG,
                                                     const int* __restrict__ hists,
                                                     int* __restrict__ tmp) {
  __shared__ int lcur[CB_SZ];
  int w = blockIdx.x, t = threadIdx.x;
  int NB2 = (N + CB_SZ - 1) / CB_SZ;
  for (int b = t; b < NB2; b += 256) lcur[b] = hists[b * NWG + w];
  __syncthreads();
  int is64 = flag[0];
  int EN = E + N;
  int i0 = w * CHUNK;
  int i1 = i0 + CHUNK; if (i1 > EN) i1 = EN;
  for (int i = i0 + t; i < i1; i += 256) {
    int s, d;
    read_edge(eg64, eg32, is64, E, i, s, d);
    int b = d >> CB_SHIFT;
    int pos = atomicAdd(&lcur[b], 1);
    tmp[pos] = (s << CB_SHIFT) | (d & (CB_SZ - 1));
  }
}

// per-bucket node counts from bucketed tmp -> cnt (coalesced, no global atomics)
__global__ __launch_bounds__(256) void bucket_cnt(const int* __restrict__ hists,
                                                  int NWG,
                                                  const int* __restrict__ tmp,
                                                  int* __restrict__ cnt, int N) {
  __shared__ int lc[CB_SZ];
  int b = blockIdx.x, t = threadIdx.x;
  for (int j = t; j < CB_SZ; j += 256) lc[j] = 0;
  __syncthreads();
  int w0 = hists[b * NWG];
  int w1 = hists[(b + 1) * NWG];  // b==NB2-1 reads hists[NB2*NWG] == EN
  for (int p = w0 + t; p < w1; p += 256)
    atomicAdd(&lc[tmp[p] & (CB_SZ - 1)], 1);
  __syncthreads();
  int n0 = b * CB_SZ;
  for (int j = t; j < CB_SZ; j += 256)
    if (n0 + j < N) cnt[n0 + j] = lc[j];
}

// final per-node sort within bucket windows
__global__ __launch_bounds__(256) void bucket_sort(const int* __restrict__ rp,
                                                   const int* __restrict__ tmp,
                                                   int* __restrict__ csr, int N) {
  __shared__ int lcur[CB_SZ];
  int b = blockIdx.x, t = threadIdx.x;
  int n0 = b * CB_SZ;
  int n1 = n0 + CB_SZ; if (n1 > N) n1 = N;
  for (int j = t; j < n1 - n0; j += 256) lcur[j] = rp[n0 + j];
  __syncthreads();
  int seg0 = rp[n0], seg1 = rp[n1];
  for (int p = seg0 + t; p < seg1; p += 256) {
    int e = tmp[p];
    int dl = e & (CB_SZ - 1);
    int s = e >> CB_SHIFT;
    int pos = atomicAdd(&lcur[dl], 1);
    csr[pos] = s;
  }
}

// ---------------- dense GEMMs ----------------
__global__ __launch_bounds__(256) void gemm1_kernel(const float* __restrict__ X,
                                                    const float* __restrict__ W,
                                                    float* __restrict__ h1, int N) {
  __shared__ float Wl[128 * 32];
  int t = threadIdx.x;
  for (int i = t; i < 128 * 32 / 4; i += 256)
    ((float4*)Wl)[i] = ((const float4*)W)[i];
  __syncthreads();
  int idx = blockIdx.x * 256 + t;  // over N*8
  if (idx >= N * 8) return;
  int n = idx >> 3, cq = idx & 7;
  const float4* X4 = (const float4*)(X + (size_t)n * 128);
  float4 acc = make_float4(0.f, 0.f, 0.f, 0.f);
#pragma unroll
  for (int k4 = 0; k4 < 32; k4++) {
    float4 x = X4[k4];
    const float4* wr = (const float4*)(Wl + (k4 * 4) * 32 + cq * 4);
    float4 w0 = wr[0], w1 = wr[8], w2 = wr[16], w3 = wr[24];
    acc.x = fmaf(x.x, w0.x, acc.x); acc.y = fmaf(x.x, w0.y, acc.y);
    acc.z = fmaf(x.x, w0.z, acc.z); acc.w = fmaf(x.x, w0.w, acc.w);
    acc.x = fmaf(x.y, w1.x, acc.x); acc.y = fmaf(x.y, w1.y, acc.y);
    acc.z = fmaf(x.y, w1.z, acc.z); acc.w = fmaf(x.y, w1.w, acc.w);
    acc.x = fmaf(x.z, w2.x, acc.x); acc.y = fmaf(x.z, w2.y, acc.y);
    acc.z = fmaf(x.z, w2.z, acc.z); acc.w = fmaf(x.z, w2.w, acc.w);
    acc.x = fmaf(x.w, w3.x, acc.x); acc.y = fmaf(x.w, w3.y, acc.y);
    acc.z = fmaf(x.w, w3.z, acc.z); acc.w = fmaf(x.w, w3.w, acc.w);
  }
  ((float4*)h1)[idx] = acc;
}

__global__ __launch_bounds__(256) void gemm2_kernel(const float* __restrict__ X,
                                                    const float* __restrict__ W,
                                                    float* __restrict__ h2, int N) {
  __shared__ float Wl[32 * 40];
  int t = threadIdx.x;
  for (int i = t; i < 32 * 40 / 4; i += 256)
    ((float4*)Wl)[i] = ((const float4*)W)[i];
  __syncthreads();
  int idx = blockIdx.x * 256 + t;  // over N*10
  if (idx >= N * 10) return;
  int n = idx / 10, cq = idx % 10;
  const float4* X4 = (const float4*)(X + (size_t)n * 32);
  float4 acc = make_float4(0.f, 0.f, 0.f, 0.f);
#pragma unroll
  for (int k4 = 0; k4 < 8; k4++) {
    float4 x = X4[k4];
    const float4* wr = (const float4*)(Wl + (k4 * 4) * 40 + cq * 4);
    float4 w0 = wr[0], w1 = wr[10], w2 = wr[20], w3 = wr[30];
    acc.x = fmaf(x.x, w0.x, acc.x); acc.y = fmaf(x.x, w0.y, acc.y);
    acc.z = fmaf(x.x, w0.z, acc.z); acc.w = fmaf(x.x, w0.w, acc.w);
    acc.x = fmaf(x.y, w1.x, acc.x); acc.y = fmaf(x.y, w1.y, acc.y);
    acc.z = fmaf(x.y, w1.z, acc.z); acc.w = fmaf(x.y, w1.w, acc.w);
    acc.x = fmaf(x.z, w2.x, acc.x); acc.y = fmaf(x.z, w2.y, acc.y);
    acc.z = fmaf(x.z, w2.z, acc.z); acc.w = fmaf(x.z, w2.w, acc.w);
    acc.x = fmaf(x.w, w3.x, acc.x); acc.y = fmaf(x.w, w3.y, acc.y);
    acc.z = fmaf(x.w, w3.z, acc.z); acc.w = fmaf(x.w, w3.w, acc.w);
  }
  ((float4*)h2)[idx] = acc;
}

// ---------------- attention scalar projections ----------------
template <int H, int C>
__global__ __launch_bounds__(256) void attn_kernel(const float* __restrict__ h,
                                                   const float* __restrict__ att_s,
                                                   const float* __restrict__ att_d,
                                                   float* __restrict__ as,
                                                   float* __restrict__ ad, int N) {
  int n = blockIdx.x * 256 + threadIdx.x;
  if (n >= N) return;
  const float* hr = h + (size_t)n * (H * C);
#pragma unroll
  for (int hh = 0; hh < H; hh++) {
    float ss = 0.f, sd = 0.f;
#pragma unroll
    for (int c = 0; c < C; c++) {
      float v = hr[hh * C + c];
      ss = fmaf(v, att_s[hh * C + c], ss);
      sd = fmaf(v, att_d[hh * C + c], sd);
    }
    as[n * H + hh] = ss;
    ad[n * H + hh] = sd;
  }
}

// ---------------- segment softmax (two-pass, stores exp(e-m)) ----------------
template <int H>
__global__ __launch_bounds__(256) void softmax_kernel(const int* __restrict__ rp,
                                                      const int* __restrict__ csr,
                                                      const float* __restrict__ as,
                                                      const float* __restrict__ ad,
                                                      float* __restrict__ alpha,
                                                      float* __restrict__ ssum, int N) {
  int t = blockIdx.x * 256 + threadIdx.x;
  if (t >= N * H) return;
  int n = t / H, h = t % H;
  int p0 = rp[n], p1 = rp[n + 1];
  float adv = ad[n * H + h];
  float m = -1e30f;
  for (int p = p0; p < p1; p++) {
    int s = csr[p];
    float e = as[s * H + h] + adv;
    e = e > 0.f ? e : 0.2f * e;
    m = fmaxf(m, e);
  }
  float sum = 0.f;
  for (int p = p0; p < p1; p++) {
    int s = csr[p];
    float e = as[s * H + h] + adv;
    e = e > 0.f ? e : 0.2f * e;
    float ex = __expf(e - m);
    sum += ex;
    alpha[p * H + h] = ex;
  }
  ssum[n * H + h] = sum;
}

// ---------------- aggregation: thread = (node, float4 of channels) ----------------
template <int H, int C, bool RELU>
__global__ __launch_bounds__(256) void agg_kernel(const int* __restrict__ rp,
                                                  const int* __restrict__ csr,
                                                  const float* __restrict__ alpha,
                                                  const float* __restrict__ ssum,
                                                  const float* __restrict__ hfeat,
                                                  const float* __restrict__ bias,
                                                  float* __restrict__ outp, int N) {
  constexpr int HC = H * C;
  constexpr int QV = HC / 4;
  int idx = blockIdx.x * 256 + threadIdx.x;  // over N*QV
  if (idx >= N * QV) return;
  int n = idx / QV, cq = idx % QV;
  int h = (cq * 4) / C;
  int p0 = rp[n], p1 = rp[n + 1];
  const float4* hf4 = (const float4*)hfeat;
  float4 acc = make_float4(0.f, 0.f, 0.f, 0.f);
  for (int p = p0; p < p1; p++) {
    int s = csr[p];
    float a = alpha[p * H + h];
    float4 v = hf4[(size_t)s * QV + cq];
    acc.x = fmaf(a, v.x, acc.x);
    acc.y = fmaf(a, v.y, acc.y);
    acc.z = fmaf(a, v.z, acc.z);
    acc.w = fmaf(a, v.w, acc.w);
  }
  float inv = 1.0f / (ssum[n * H + h] + 1e-16f);
  float4 b = ((const float4*)bias)[cq];
  float4 r;
  r.x = acc.x * inv + b.x;
  r.y = acc.y * inv + b.y;
  r.z = acc.z * inv + b.z;
  r.w = acc.w * inv + b.w;
  if (RELU) {
    r.x = fmaxf(r.x, 0.f); r.y = fmaxf(r.y, 0.f);
    r.z = fmaxf(r.z, 0.f); r.w = fmaxf(r.w, 0.f);
  }
  ((float4*)outp)[idx] = r;
}

// ---------------- host launcher ----------------
extern "C" void kernel_launch(void* const* d_in, const int* in_sizes, int n_in,
                              void* d_out, int out_size, void* d_ws, size_t ws_size,
                              hipStream_t stream) {
  const float* X    = (const float*)d_in[0];
  const long long* eg64 = (const long long*)d_in[1];
  const int* eg32   = (const int*)d_in[1];
  const float* W1   = (const float*)d_in[3];
  const float* as1w = (const float*)d_in[4];
  const float* ad1w = (const float*)d_in[5];
  const float* b1   = (const float*)d_in[6];
  const float* W2   = (const float*)d_in[7];
  const float* as2w = (const float*)d_in[8];
  const float* ad2w = (const float*)d_in[9];
  const float* b2   = (const float*)d_in[10];
  float* out = (float*)d_out;

  const int N  = in_sizes[0] / 128;
  const int E  = in_sizes[1] / 2;
  const int EN = E + N;
  const int NB2 = (N + CB_SZ - 1) / CB_SZ;
  const int NWG = (EN + CHUNK - 1) / CHUNK;
  const int NH  = NB2 * NWG;

  char* wbase = (char*)d_ws;
  size_t off = 0;
  auto alloc = [&](size_t bytes) -> void* {
    void* p = wbase + off;
    off += (bytes + 255) & ~(size_t)255;
    return p;
  };

  float* h1  = (float*)alloc((size_t)N * 32 * 4);
  float* x1  = (float*)alloc((size_t)N * 32 * 4);
  float* h2  = (float*)alloc((size_t)N * 40 * 4);
  float* as1 = (float*)alloc((size_t)N * 2 * 4);
  float* ad1 = (float*)alloc((size_t)N * 2 * 4);
  float* s1  = (float*)alloc((size_t)N * 2 * 4);
  float* as2 = (float*)alloc((size_t)N * 4);
  float* ad2 = (float*)alloc((size_t)N * 4);
  float* s2  = (float*)alloc((size_t)N * 4);
  int* cnt    = (int*)alloc((size_t)N * 4);
  int* rp     = (int*)alloc((size_t)(N + 1) * 4);
  int* histg  = (int*)alloc((size_t)NH * 4);
  int* hists  = (int*)alloc((size_t)(NH + 1) * 4);
  int* bsum   = (int*)alloc(1024 * 4);
  int* boff   = (int*)alloc(1024 * 4);
  int* flag   = (int*)alloc(256);
  int* csr    = (int*)alloc((size_t)EN * 4);
  float* al1  = (float*)alloc((size_t)EN * 2 * 4);
  float* al2  = (float*)alloc((size_t)EN * 4);
  int* tmp = (int*)al1;  // alias: tmp dead before al1 is written
  (void)ws_size; (void)n_in; (void)out_size;

  const int gN  = (N + 255) / 256;
  const int nbH = (NH + 1023) / 1024;
  const int nbN = (N + 1023) / 1024;

  detect_kernel<<<1, 256, 0, stream>>>(eg32, E, flag);

  // CSR build (atomic-free)
  chunk_hist<<<NWG, 256, 0, stream>>>(eg64, eg32, flag, E, N, NWG, histg);
  scan_blocks<<<nbH, 1024, 0, stream>>>(histg, hists, bsum, NH);
  scan_sums<<<1, 64, 0, stream>>>(bsum, boff, nbH);
  scan_add<<<nbH, 1024, 0, stream>>>(hists, boff, NH, EN);
  chunk_scatter<<<NWG, 256, 0, stream>>>(eg64, eg32, flag, E, N, NWG, hists, tmp);
  bucket_cnt<<<NB2, 256, 0, stream>>>(hists, NWG, tmp, cnt, N);
  scan_blocks<<<nbN, 1024, 0, stream>>>(cnt, rp, bsum, N);
  scan_sums<<<1, 64, 0, stream>>>(bsum, boff, nbN);
  scan_add<<<nbN, 1024, 0, stream>>>(rp, boff, N, EN);
  bucket_sort<<<NB2, 256, 0, stream>>>(rp, tmp, csr, N);

  // Layer 1
  gemm1_kernel<<<(N * 8 + 255) / 256, 256, 0, stream>>>(X, W1, h1, N);
  attn_kernel<2, 16><<<gN, 256, 0, stream>>>(h1, as1w, ad1w, as1, ad1, N);
  softmax_kernel<2><<<(N * 2 + 255) / 256, 256, 0, stream>>>(rp, csr, as1, ad1, al1, s1, N);
  agg_kernel<2, 16, true><<<(N * 8 + 255) / 256, 256, 0, stream>>>(rp, csr, al1, s1, h1, b1, x1, N);

  // Layer 2
  gemm2_kernel<<<(N * 10 + 255) / 256, 256, 0, stream>>>(x1, W2, h2, N);
  attn_kernel<1, 40><<<gN, 256, 0, stream>>>(h2, as2w, ad2w, as2, ad2, N);
  softmax_kernel<1><<<gN, 256, 0, stream>>>(rp, csr, as2, ad2, al2, s2, N);
  agg_kernel<1, 40, false><<<(N * 10 + 255) / 256, 256, 0, stream>>>(rp, csr, al2, s2, h2, b2, out, N);
}

// Round 4
// 492.744 us; speedup vs baseline: 3.0729x; 1.3896x over previous
//
#include <hip/hip_runtime.h>

// GAT 2-layer forward on MI355X.
// Round 3 -> 4: fuse softmax into aggregation (softmax is shift-invariant and
// e is bounded, so skip max-subtraction; accumulate num=sum(exp*h) and
// den=sum(exp) in one pass). Deletes softmax kernels + alpha arrays.
// Layer-1 gather payload converted to fp16 (64B/edge instead of 128B);
// layer-2 stays fp32 (precision budget).
// CSR build: unchanged atomic-free multisplit (r3: 1514->685us).

#define DEVFN __device__ __forceinline__
#define CB_SHIFT 9
#define CB_SZ 512
#define CHUNK 8192

DEVFN unsigned short f2h(float f) {
  _Float16 h = (_Float16)f;
  unsigned short u;
  __builtin_memcpy(&u, &h, 2);
  return u;
}
DEVFN float h2f(unsigned short u) {
  _Float16 h;
  __builtin_memcpy(&h, &u, 2);
  return (float)h;
}

// ---------------- edge dtype detection (int64 vs int32) ----------------
__global__ void detect_kernel(const int* eg32, int E, int* flag) {
  __shared__ int any;
  if (threadIdx.x == 0) any = 0;
  __syncthreads();
  for (int k = threadIdx.x; k < 2048 && k < E; k += 256) {
    if (eg32[2 * k + 1] != 0) atomicOr(&any, 1);
  }
  __syncthreads();
  if (threadIdx.x == 0) flag[0] = any ? 0 : 1;  // 1 => int64
}

DEVFN int read_dst(const long long* eg64, const int* eg32, int is64, int E, int i) {
  if (i >= E) return i - E;
  return is64 ? (int)eg64[E + i] : eg32[E + i];
}

DEVFN void read_edge(const long long* eg64, const int* eg32, int is64, int E,
                     int i, int& s, int& d) {
  if (i >= E) { s = d = i - E; return; }
  if (is64) { s = (int)eg64[i]; d = (int)eg64[E + i]; }
  else      { s = eg32[i];      d = eg32[E + i]; }
}

// ---------------- generic scan (blocks of 1024) ----------------
__global__ void scan_blocks(const int* __restrict__ cnt, int* __restrict__ rp,
                            int* __restrict__ bsum, int n) {
  __shared__ int buf[2][1024];
  int t = threadIdx.x;
  int gid = blockIdx.x * 1024 + t;
  int v = (gid < n) ? cnt[gid] : 0;
  buf[0][t] = v;
  __syncthreads();
  int pin = 0;
  for (int offd = 1; offd < 1024; offd <<= 1) {
    int nv = buf[pin][t];
    if (t >= offd) nv += buf[pin][t - offd];
    buf[1 - pin][t] = nv;
    pin = 1 - pin;
    __syncthreads();
  }
  int inc = buf[pin][t];
  if (gid < n) rp[gid] = inc - v;  // exclusive within block
  if (t == 1023) bsum[blockIdx.x] = inc;
}

__global__ void scan_sums(const int* bsum, int* boff, int nb) {
  if (blockIdx.x == 0 && threadIdx.x == 0) {
    int r = 0;
    for (int i = 0; i < nb; i++) { boff[i] = r; r += bsum[i]; }
  }
}

__global__ void scan_add(int* rp, const int* boff, int n, int total) {
  int i = blockIdx.x * 1024 + threadIdx.x;
  if (i < n) rp[i] = rp[i] + boff[blockIdx.x];
  if (i == 0) rp[n] = total;
}

// ---------------- CSR build (atomic-free multisplit) ----------------
__global__ __launch_bounds__(256) void chunk_hist(const long long* eg64,
                                                  const int* eg32, const int* flag,
                                                  int E, int N, int NWG,
                                                  int* __restrict__ histg) {
  __shared__ int lh[CB_SZ];
  int w = blockIdx.x, t = threadIdx.x;
  int NB2 = (N + CB_SZ - 1) / CB_SZ;
  for (int j = t; j < NB2; j += 256) lh[j] = 0;
  __syncthreads();
  int is64 = flag[0];
  int EN = E + N;
  int i0 = w * CHUNK;
  int i1 = i0 + CHUNK; if (i1 > EN) i1 = EN;
  for (int i = i0 + t; i < i1; i += 256) {
    int d = read_dst(eg64, eg32, is64, E, i);
    atomicAdd(&lh[d >> CB_SHIFT], 1);
  }
  __syncthreads();
  for (int b = t; b < NB2; b += 256) histg[b * NWG + w] = lh[b];
}

__global__ __launch_bounds__(256) void chunk_scatter(const long long* eg64,
                                                     const int* eg32, const int* flag,
                                                     int E, int N, int NWG,
                                                     const int* __restrict__ hists,
                                                     int* __restrict__ tmp) {
  __shared__ int lcur[CB_SZ];
  int w = blockIdx.x, t = threadIdx.x;
  int NB2 = (N + CB_SZ - 1) / CB_SZ;
  for (int b = t; b < NB2; b += 256) lcur[b] = hists[b * NWG + w];
  __syncthreads();
  int is64 = flag[0];
  int EN = E + N;
  int i0 = w * CHUNK;
  int i1 = i0 + CHUNK; if (i1 > EN) i1 = EN;
  for (int i = i0 + t; i < i1; i += 256) {
    int s, d;
    read_edge(eg64, eg32, is64, E, i, s, d);
    int b = d >> CB_SHIFT;
    int pos = atomicAdd(&lcur[b], 1);
    tmp[pos] = (s << CB_SHIFT) | (d & (CB_SZ - 1));
  }
}

__global__ __launch_bounds__(256) void bucket_cnt(const int* __restrict__ hists,
                                                  int NWG,
                                                  const int* __restrict__ tmp,
                                                  int* __restrict__ cnt, int N) {
  __shared__ int lc[CB_SZ];
  int b = blockIdx.x, t = threadIdx.x;
  for (int j = t; j < CB_SZ; j += 256) lc[j] = 0;
  __syncthreads();
  int w0 = hists[b * NWG];
  int w1 = hists[(b + 1) * NWG];
  for (int p = w0 + t; p < w1; p += 256)
    atomicAdd(&lc[tmp[p] & (CB_SZ - 1)], 1);
  __syncthreads();
  int n0 = b * CB_SZ;
  for (int j = t; j < CB_SZ; j += 256)
    if (n0 + j < N) cnt[n0 + j] = lc[j];
}

__global__ __launch_bounds__(256) void bucket_sort(const int* __restrict__ rp,
                                                   const int* __restrict__ tmp,
                                                   int* __restrict__ csr, int N) {
  __shared__ int lcur[CB_SZ];
  int b = blockIdx.x, t = threadIdx.x;
  int n0 = b * CB_SZ;
  int n1 = n0 + CB_SZ; if (n1 > N) n1 = N;
  for (int j = t; j < n1 - n0; j += 256) lcur[j] = rp[n0 + j];
  __syncthreads();
  int seg0 = rp[n0], seg1 = rp[n1];
  for (int p = seg0 + t; p < seg1; p += 256) {
    int e = tmp[p];
    int dl = e & (CB_SZ - 1);
    int s = e >> CB_SHIFT;
    int pos = atomicAdd(&lcur[dl], 1);
    csr[pos] = s;
  }
}

// ---------------- dense GEMMs ----------------
__global__ __launch_bounds__(256) void gemm1_kernel(const float* __restrict__ X,
                                                    const float* __restrict__ W,
                                                    float* __restrict__ h1, int N) {
  __shared__ float Wl[128 * 32];
  int t = threadIdx.x;
  for (int i = t; i < 128 * 32 / 4; i += 256)
    ((float4*)Wl)[i] = ((const float4*)W)[i];
  __syncthreads();
  int idx = blockIdx.x * 256 + t;  // over N*8
  if (idx >= N * 8) return;
  int n = idx >> 3, cq = idx & 7;
  const float4* X4 = (const float4*)(X + (size_t)n * 128);
  float4 acc = make_float4(0.f, 0.f, 0.f, 0.f);
#pragma unroll
  for (int k4 = 0; k4 < 32; k4++) {
    float4 x = X4[k4];
    const float4* wr = (const float4*)(Wl + (k4 * 4) * 32 + cq * 4);
    float4 w0 = wr[0], w1 = wr[8], w2 = wr[16], w3 = wr[24];
    acc.x = fmaf(x.x, w0.x, acc.x); acc.y = fmaf(x.x, w0.y, acc.y);
    acc.z = fmaf(x.x, w0.z, acc.z); acc.w = fmaf(x.x, w0.w, acc.w);
    acc.x = fmaf(x.y, w1.x, acc.x); acc.y = fmaf(x.y, w1.y, acc.y);
    acc.z = fmaf(x.y, w1.z, acc.z); acc.w = fmaf(x.y, w1.w, acc.w);
    acc.x = fmaf(x.z, w2.x, acc.x); acc.y = fmaf(x.z, w2.y, acc.y);
    acc.z = fmaf(x.z, w2.z, acc.z); acc.w = fmaf(x.z, w2.w, acc.w);
    acc.x = fmaf(x.w, w3.x, acc.x); acc.y = fmaf(x.w, w3.y, acc.y);
    acc.z = fmaf(x.w, w3.z, acc.z); acc.w = fmaf(x.w, w3.w, acc.w);
  }
  ((float4*)h1)[idx] = acc;
}

__global__ __launch_bounds__(256) void gemm2_kernel(const float* __restrict__ X,
                                                    const float* __restrict__ W,
                                                    float* __restrict__ h2, int N) {
  __shared__ float Wl[32 * 40];
  int t = threadIdx.x;
  for (int i = t; i < 32 * 40 / 4; i += 256)
    ((float4*)Wl)[i] = ((const float4*)W)[i];
  __syncthreads();
  int idx = blockIdx.x * 256 + t;  // over N*10
  if (idx >= N * 10) return;
  int n = idx / 10, cq = idx % 10;
  const float4* X4 = (const float4*)(X + (size_t)n * 32);
  float4 acc = make_float4(0.f, 0.f, 0.f, 0.f);
#pragma unroll
  for (int k4 = 0; k4 < 8; k4++) {
    float4 x = X4[k4];
    const float4* wr = (const float4*)(Wl + (k4 * 4) * 40 + cq * 4);
    float4 w0 = wr[0], w1 = wr[10], w2 = wr[20], w3 = wr[30];
    acc.x = fmaf(x.x, w0.x, acc.x); acc.y = fmaf(x.x, w0.y, acc.y);
    acc.z = fmaf(x.x, w0.z, acc.z); acc.w = fmaf(x.x, w0.w, acc.w);
    acc.x = fmaf(x.y, w1.x, acc.x); acc.y = fmaf(x.y, w1.y, acc.y);
    acc.z = fmaf(x.y, w1.z, acc.z); acc.w = fmaf(x.y, w1.w, acc.w);
    acc.x = fmaf(x.z, w2.x, acc.x); acc.y = fmaf(x.z, w2.y, acc.y);
    acc.z = fmaf(x.z, w2.z, acc.z); acc.w = fmaf(x.z, w2.w, acc.w);
    acc.x = fmaf(x.w, w3.x, acc.x); acc.y = fmaf(x.w, w3.y, acc.y);
    acc.z = fmaf(x.w, w3.z, acc.z); acc.w = fmaf(x.w, w3.w, acc.w);
  }
  ((float4*)h2)[idx] = acc;
}

// ---------------- attention scalar projections ----------------
template <int H, int C>
__global__ __launch_bounds__(256) void attn_kernel(const float* __restrict__ h,
                                                   const float* __restrict__ att_s,
                                                   const float* __restrict__ att_d,
                                                   float* __restrict__ as,
                                                   float* __restrict__ ad, int N) {
  int n = blockIdx.x * 256 + threadIdx.x;
  if (n >= N) return;
  const float* hr = h + (size_t)n * (H * C);
#pragma unroll
  for (int hh = 0; hh < H; hh++) {
    float ss = 0.f, sd = 0.f;
#pragma unroll
    for (int c = 0; c < C; c++) {
      float v = hr[hh * C + c];
      ss = fmaf(v, att_s[hh * C + c], ss);
      sd = fmaf(v, att_d[hh * C + c], sd);
    }
    as[n * H + hh] = ss;
    ad[n * H + hh] = sd;
  }
}

// ---------------- h1 -> fp16 conversion (N*4 threads, 8 ch each) ----------------
__global__ __launch_bounds__(256) void conv_h1(const float* __restrict__ h1,
                                               uint4* __restrict__ h1h, int N) {
  int idx = blockIdx.x * 256 + threadIdx.x;  // over N*4
  if (idx >= N * 4) return;
  float4 a = ((const float4*)h1)[idx * 2];
  float4 b = ((const float4*)h1)[idx * 2 + 1];
  uint4 u;
  u.x = (unsigned)f2h(a.x) | ((unsigned)f2h(a.y) << 16);
  u.y = (unsigned)f2h(a.z) | ((unsigned)f2h(a.w) << 16);
  u.z = (unsigned)f2h(b.x) | ((unsigned)f2h(b.y) << 16);
  u.w = (unsigned)f2h(b.z) | ((unsigned)f2h(b.w) << 16);
  h1h[idx] = u;
}

// ---------------- fused softmax+agg, layer 1 (fp16 payload) ----------------
// thread = (node, quarter-row of 8 channels); head = cq>>1
__global__ __launch_bounds__(256) void agg1_fused(const int* __restrict__ rp,
                                                  const int* __restrict__ csr,
                                                  const float* __restrict__ as,
                                                  const float* __restrict__ ad,
                                                  const uint4* __restrict__ h1h,
                                                  const float* __restrict__ bias,
                                                  float* __restrict__ x1, int N) {
  int idx = blockIdx.x * 256 + threadIdx.x;  // over N*4
  if (idx >= N * 4) return;
  int n = idx >> 2, cq = idx & 3;
  int h = cq >> 1;
  int p0 = rp[n], p1 = rp[n + 1];
  float adv = ad[n * 2 + h];
  float acc[8] = {0, 0, 0, 0, 0, 0, 0, 0};
  float ssum = 0.f;
  for (int p = p0; p < p1; p++) {
    int s = csr[p];
    float e = as[s * 2 + h] + adv;
    e = e > 0.f ? e : 0.2f * e;
    float ex = __expf(e);
    ssum += ex;
    uint4 u = h1h[s * 4 + cq];
    acc[0] = fmaf(ex, h2f(u.x & 0xffff), acc[0]);
    acc[1] = fmaf(ex, h2f(u.x >> 16),    acc[1]);
    acc[2] = fmaf(ex, h2f(u.y & 0xffff), acc[2]);
    acc[3] = fmaf(ex, h2f(u.y >> 16),    acc[3]);
    acc[4] = fmaf(ex, h2f(u.z & 0xffff), acc[4]);
    acc[5] = fmaf(ex, h2f(u.z >> 16),    acc[5]);
    acc[6] = fmaf(ex, h2f(u.w & 0xffff), acc[6]);
    acc[7] = fmaf(ex, h2f(u.w >> 16),    acc[7]);
  }
  float inv = 1.0f / (ssum + 1e-16f);
  float4 r0, r1;
  const float4* b4 = (const float4*)bias;
  float4 ba = b4[cq * 2], bb = b4[cq * 2 + 1];
  r0.x = fmaxf(fmaf(acc[0], inv, ba.x), 0.f);
  r0.y = fmaxf(fmaf(acc[1], inv, ba.y), 0.f);
  r0.z = fmaxf(fmaf(acc[2], inv, ba.z), 0.f);
  r0.w = fmaxf(fmaf(acc[3], inv, ba.w), 0.f);
  r1.x = fmaxf(fmaf(acc[4], inv, bb.x), 0.f);
  r1.y = fmaxf(fmaf(acc[5], inv, bb.y), 0.f);
  r1.z = fmaxf(fmaf(acc[6], inv, bb.z), 0.f);
  r1.w = fmaxf(fmaf(acc[7], inv, bb.w), 0.f);
  ((float4*)x1)[idx * 2]     = r0;
  ((float4*)x1)[idx * 2 + 1] = r1;
}

// ---------------- fused softmax+agg, layer 2 (fp32 payload, H=1,C=40) --------
__global__ __launch_bounds__(256) void agg2_fused(const int* __restrict__ rp,
                                                  const int* __restrict__ csr,
                                                  const float* __restrict__ as,
                                                  const float* __restrict__ ad,
                                                  const float* __restrict__ hfeat,
                                                  const float* __restrict__ bias,
                                                  float* __restrict__ outp, int N) {
  int idx = blockIdx.x * 256 + threadIdx.x;  // over N*10
  if (idx >= N * 10) return;
  int n = idx / 10, cq = idx % 10;
  int p0 = rp[n], p1 = rp[n + 1];
  float adv = ad[n];
  const float4* hf4 = (const float4*)hfeat;
  float4 acc = make_float4(0.f, 0.f, 0.f, 0.f);
  float ssum = 0.f;
  for (int p = p0; p < p1; p++) {
    int s = csr[p];
    float e = as[s] + adv;
    e = e > 0.f ? e : 0.2f * e;
    float ex = __expf(e);
    ssum += ex;
    float4 v = hf4[(size_t)s * 10 + cq];
    acc.x = fmaf(ex, v.x, acc.x);
    acc.y = fmaf(ex, v.y, acc.y);
    acc.z = fmaf(ex, v.z, acc.z);
    acc.w = fmaf(ex, v.w, acc.w);
  }
  float inv = 1.0f / (ssum + 1e-16f);
  float4 b = ((const float4*)bias)[cq];
  float4 r;
  r.x = fmaf(acc.x, inv, b.x);
  r.y = fmaf(acc.y, inv, b.y);
  r.z = fmaf(acc.z, inv, b.z);
  r.w = fmaf(acc.w, inv, b.w);
  ((float4*)outp)[idx] = r;
}

// ---------------- host launcher ----------------
extern "C" void kernel_launch(void* const* d_in, const int* in_sizes, int n_in,
                              void* d_out, int out_size, void* d_ws, size_t ws_size,
                              hipStream_t stream) {
  const float* X    = (const float*)d_in[0];
  const long long* eg64 = (const long long*)d_in[1];
  const int* eg32   = (const int*)d_in[1];
  const float* W1   = (const float*)d_in[3];
  const float* as1w = (const float*)d_in[4];
  const float* ad1w = (const float*)d_in[5];
  const float* b1   = (const float*)d_in[6];
  const float* W2   = (const float*)d_in[7];
  const float* as2w = (const float*)d_in[8];
  const float* ad2w = (const float*)d_in[9];
  const float* b2   = (const float*)d_in[10];
  float* out = (float*)d_out;

  const int N  = in_sizes[0] / 128;
  const int E  = in_sizes[1] / 2;
  const int EN = E + N;
  const int NB2 = (N + CB_SZ - 1) / CB_SZ;
  const int NWG = (EN + CHUNK - 1) / CHUNK;
  const int NH  = NB2 * NWG;

  char* wbase = (char*)d_ws;
  size_t off = 0;
  auto alloc = [&](size_t bytes) -> void* {
    void* p = wbase + off;
    off += (bytes + 255) & ~(size_t)255;
    return p;
  };

  float* h1  = (float*)alloc((size_t)N * 32 * 4);
  float* x1  = (float*)alloc((size_t)N * 32 * 4);
  float* h2  = (float*)alloc((size_t)N * 40 * 4);
  uint4* h1h = (uint4*)alloc((size_t)N * 32 * 2);
  float* as1 = (float*)alloc((size_t)N * 2 * 4);
  float* ad1 = (float*)alloc((size_t)N * 2 * 4);
  float* as2 = (float*)alloc((size_t)N * 4);
  float* ad2 = (float*)alloc((size_t)N * 4);
  int* cnt    = (int*)alloc((size_t)N * 4);
  int* rp     = (int*)alloc((size_t)(N + 1) * 4);
  int* histg  = (int*)alloc((size_t)NH * 4);
  int* hists  = (int*)alloc((size_t)(NH + 1) * 4);
  int* bsum   = (int*)alloc(1024 * 4);
  int* boff   = (int*)alloc(1024 * 4);
  int* flag   = (int*)alloc(256);
  int* csr    = (int*)alloc((size_t)EN * 4);
  int* tmp    = (int*)alloc((size_t)EN * 4);
  (void)ws_size; (void)n_in; (void)out_size;

  const int gN  = (N + 255) / 256;
  const int nbH = (NH + 1023) / 1024;
  const int nbN = (N + 1023) / 1024;

  detect_kernel<<<1, 256, 0, stream>>>(eg32, E, flag);

  // CSR build (atomic-free)
  chunk_hist<<<NWG, 256, 0, stream>>>(eg64, eg32, flag, E, N, NWG, histg);
  scan_blocks<<<nbH, 1024, 0, stream>>>(histg, hists, bsum, NH);
  scan_sums<<<1, 64, 0, stream>>>(bsum, boff, nbH);
  scan_add<<<nbH, 1024, 0, stream>>>(hists, boff, NH, EN);
  chunk_scatter<<<NWG, 256, 0, stream>>>(eg64, eg32, flag, E, N, NWG, hists, tmp);
  bucket_cnt<<<NB2, 256, 0, stream>>>(hists, NWG, tmp, cnt, N);
  scan_blocks<<<nbN, 1024, 0, stream>>>(cnt, rp, bsum, N);
  scan_sums<<<1, 64, 0, stream>>>(bsum, boff, nbN);
  scan_add<<<nbN, 1024, 0, stream>>>(rp, boff, N, EN);
  bucket_sort<<<NB2, 256, 0, stream>>>(rp, tmp, csr, N);

  // Layer 1
  gemm1_kernel<<<(N * 8 + 255) / 256, 256, 0, stream>>>(X, W1, h1, N);
  attn_kernel<2, 16><<<gN, 256, 0, stream>>>(h1, as1w, ad1w, as1, ad1, N);
  conv_h1<<<(N * 4 + 255) / 256, 256, 0, stream>>>(h1, h1h, N);
  agg1_fused<<<(N * 4 + 255) / 256, 256, 0, stream>>>(rp, csr, as1, ad1, h1h, b1, x1, N);

  // Layer 2
  gemm2_kernel<<<(N * 10 + 255) / 256, 256, 0, stream>>>(x1, W2, h2, N);
  attn_kernel<1, 40><<<gN, 256, 0, stream>>>(h2, as2w, ad2w, as2, ad2, N);
  agg2_fused<<<(N * 10 + 255) / 256, 256, 0, stream>>>(rp, csr, as2, ad2, h2, b2, out, N);
}

// Round 5
// 452.865 us; speedup vs baseline: 3.3435x; 1.0881x over previous
//
#include <hip/hip_runtime.h>

// GAT 2-layer forward on MI355X.
// Round 5:
//  - h2 payload -> fp16 padded to 128B/row (1 cache line per edge-gather
//    instead of 1.625; r4 counters showed agg2 is line-granularity-bound).
//  - gemm+attn+fp16pack fused into one kernel per layer (thread = node,
//    acc in regs, W/att in LDS broadcast); deletes attn x2, conv, fp32 h1/h2.
//  - bucket_rp: per-bucket counts + in-LDS scan -> rp directly from bucketed
//    tmp windows (replaces cnt + 3-dispatch global scan).
//  - 12 dispatches total (was 19).

#define DEVFN __device__ __forceinline__
#define CB_SHIFT 9
#define CB_SZ 512
#define CHUNK 8192

DEVFN unsigned short f2h(float f) {
  _Float16 h = (_Float16)f;
  unsigned short u;
  __builtin_memcpy(&u, &h, 2);
  return u;
}
DEVFN float h2f(unsigned short u) {
  _Float16 h;
  __builtin_memcpy(&h, &u, 2);
  return (float)h;
}

// ---------------- edge dtype detection (int64 vs int32) ----------------
__global__ void detect_kernel(const int* eg32, int E, int* flag) {
  __shared__ int any;
  if (threadIdx.x == 0) any = 0;
  __syncthreads();
  for (int k = threadIdx.x; k < 2048 && k < E; k += 256) {
    if (eg32[2 * k + 1] != 0) atomicOr(&any, 1);
  }
  __syncthreads();
  if (threadIdx.x == 0) flag[0] = any ? 0 : 1;  // 1 => int64
}

DEVFN int read_dst(const long long* eg64, const int* eg32, int is64, int E, int i) {
  if (i >= E) return i - E;
  return is64 ? (int)eg64[E + i] : eg32[E + i];
}

DEVFN void read_edge(const long long* eg64, const int* eg32, int is64, int E,
                     int i, int& s, int& d) {
  if (i >= E) { s = d = i - E; return; }
  if (is64) { s = (int)eg64[i]; d = (int)eg64[E + i]; }
  else      { s = eg32[i];      d = eg32[E + i]; }
}

// ---------------- generic scan (blocks of 1024) for chunk histograms --------
__global__ void scan_blocks(const int* __restrict__ cnt, int* __restrict__ rp,
                            int* __restrict__ bsum, int n) {
  __shared__ int buf[2][1024];
  int t = threadIdx.x;
  int gid = blockIdx.x * 1024 + t;
  int v = (gid < n) ? cnt[gid] : 0;
  buf[0][t] = v;
  __syncthreads();
  int pin = 0;
  for (int offd = 1; offd < 1024; offd <<= 1) {
    int nv = buf[pin][t];
    if (t >= offd) nv += buf[pin][t - offd];
    buf[1 - pin][t] = nv;
    pin = 1 - pin;
    __syncthreads();
  }
  int inc = buf[pin][t];
  if (gid < n) rp[gid] = inc - v;  // exclusive within block
  if (t == 1023) bsum[blockIdx.x] = inc;
}

__global__ void scan_sums(const int* bsum, int* boff, int nb) {
  if (blockIdx.x == 0 && threadIdx.x == 0) {
    int r = 0;
    for (int i = 0; i < nb; i++) { boff[i] = r; r += bsum[i]; }
  }
}

__global__ void scan_add(int* rp, const int* boff, int n, int total) {
  int i = blockIdx.x * 1024 + threadIdx.x;
  if (i < n) rp[i] = rp[i] + boff[blockIdx.x];
  if (i == 0) rp[n] = total;
}

// ---------------- CSR build (atomic-free multisplit) ----------------
__global__ __launch_bounds__(256) void chunk_hist(const long long* eg64,
                                                  const int* eg32, const int* flag,
                                                  int E, int N, int NWG,
                                                  int* __restrict__ histg) {
  __shared__ int lh[CB_SZ];
  int w = blockIdx.x, t = threadIdx.x;
  int NB2 = (N + CB_SZ - 1) / CB_SZ;
  for (int j = t; j < NB2; j += 256) lh[j] = 0;
  __syncthreads();
  int is64 = flag[0];
  int EN = E + N;
  int i0 = w * CHUNK;
  int i1 = i0 + CHUNK; if (i1 > EN) i1 = EN;
  for (int i = i0 + t; i < i1; i += 256) {
    int d = read_dst(eg64, eg32, is64, E, i);
    atomicAdd(&lh[d >> CB_SHIFT], 1);
  }
  __syncthreads();
  for (int b = t; b < NB2; b += 256) histg[b * NWG + w] = lh[b];
}

__global__ __launch_bounds__(256) void chunk_scatter(const long long* eg64,
                                                     const int* eg32, const int* flag,
                                                     int E, int N, int NWG,
                                                     const int* __restrict__ hists,
                                                     int* __restrict__ tmp) {
  __shared__ int lcur[CB_SZ];
  int w = blockIdx.x, t = threadIdx.x;
  int NB2 = (N + CB_SZ - 1) / CB_SZ;
  for (int b = t; b < NB2; b += 256) lcur[b] = hists[b * NWG + w];
  __syncthreads();
  int is64 = flag[0];
  int EN = E + N;
  int i0 = w * CHUNK;
  int i1 = i0 + CHUNK; if (i1 > EN) i1 = EN;
  for (int i = i0 + t; i < i1; i += 256) {
    int s, d;
    read_edge(eg64, eg32, is64, E, i, s, d);
    int b = d >> CB_SHIFT;
    int pos = atomicAdd(&lcur[b], 1);
    tmp[pos] = (s << CB_SHIFT) | (d & (CB_SZ - 1));
  }
}

// per-bucket node counts + in-LDS scan -> rp (replaces cnt + global scan)
__global__ __launch_bounds__(256) void bucket_rp(const int* __restrict__ hists,
                                                 int NWG,
                                                 const int* __restrict__ tmp,
                                                 int* __restrict__ rp, int N, int EN) {
  __shared__ int lc[CB_SZ];
  __shared__ int ps[256];
  int b = blockIdx.x, t = threadIdx.x;
  for (int j = t; j < CB_SZ; j += 256) lc[j] = 0;
  __syncthreads();
  int w0 = hists[b * NWG];
  int w1 = hists[(b + 1) * NWG];  // last bucket reads hists[NB2*NWG] == EN
  for (int p = w0 + t; p < w1; p += 256)
    atomicAdd(&lc[tmp[p] & (CB_SZ - 1)], 1);
  __syncthreads();
  int a = lc[2 * t], c = lc[2 * t + 1];
  ps[t] = a + c;
  __syncthreads();
  for (int off = 1; off < 256; off <<= 1) {
    int v = ps[t];
    int u = (t >= off) ? ps[t - off] : 0;
    __syncthreads();
    ps[t] = v + u;
    __syncthreads();
  }
  int base = w0 + ps[t] - (a + c);  // exclusive prefix within bucket
  int n0 = b * CB_SZ;
  if (n0 + 2 * t < N) rp[n0 + 2 * t] = base;
  if (n0 + 2 * t + 1 < N) rp[n0 + 2 * t + 1] = base + a;
  if (b == (int)gridDim.x - 1 && t == 0) rp[N] = EN;
}

__global__ __launch_bounds__(256) void bucket_sort(const int* __restrict__ rp,
                                                   const int* __restrict__ tmp,
                                                   int* __restrict__ csr, int N) {
  __shared__ int lcur[CB_SZ];
  int b = blockIdx.x, t = threadIdx.x;
  int n0 = b * CB_SZ;
  int n1 = n0 + CB_SZ; if (n1 > N) n1 = N;
  for (int j = t; j < n1 - n0; j += 256) lcur[j] = rp[n0 + j];
  __syncthreads();
  int seg0 = rp[n0], seg1 = rp[n1];
  for (int p = seg0 + t; p < seg1; p += 256) {
    int e = tmp[p];
    int dl = e & (CB_SZ - 1);
    int s = e >> CB_SHIFT;
    int pos = atomicAdd(&lcur[dl], 1);
    csr[pos] = s;
  }
}

// ---------------- fused GEMM + attn + fp16 pack, layer 1 ----------------
// thread = node; h1 row (32ch) in regs; writes h1h (fp16, 64B row), as1, ad1
__global__ __launch_bounds__(256) void gemm1f(const float* __restrict__ X,
                                              const float* __restrict__ W,
                                              const float* __restrict__ att_s,
                                              const float* __restrict__ att_d,
                                              uint4* __restrict__ h1h,
                                              float* __restrict__ as1,
                                              float* __restrict__ ad1, int N) {
  __shared__ float Wl[128 * 32];
  __shared__ float Asl[32], Adl[32];
  int t = threadIdx.x;
  for (int i = t; i < 1024; i += 256)
    ((float4*)Wl)[i] = ((const float4*)W)[i];
  if (t < 32) { Asl[t] = att_s[t]; Adl[t] = att_d[t]; }
  __syncthreads();
  int n = blockIdx.x * 256 + t;
  if (n >= N) return;
  const float4* X4 = (const float4*)(X + (size_t)n * 128);
  float acc[32];
#pragma unroll
  for (int c = 0; c < 32; c++) acc[c] = 0.f;
  for (int k4 = 0; k4 < 32; k4++) {
    float4 x = X4[k4];
    const float4* w4 = (const float4*)(Wl + k4 * 128);
#pragma unroll
    for (int c4 = 0; c4 < 8; c4++) {
      float4 w0 = w4[c4], w1 = w4[8 + c4], w2 = w4[16 + c4], w3 = w4[24 + c4];
      float* A = acc + c4 * 4;
      A[0] = fmaf(x.x, w0.x, A[0]); A[1] = fmaf(x.x, w0.y, A[1]);
      A[2] = fmaf(x.x, w0.z, A[2]); A[3] = fmaf(x.x, w0.w, A[3]);
      A[0] = fmaf(x.y, w1.x, A[0]); A[1] = fmaf(x.y, w1.y, A[1]);
      A[2] = fmaf(x.y, w1.z, A[2]); A[3] = fmaf(x.y, w1.w, A[3]);
      A[0] = fmaf(x.z, w2.x, A[0]); A[1] = fmaf(x.z, w2.y, A[1]);
      A[2] = fmaf(x.z, w2.z, A[2]); A[3] = fmaf(x.z, w2.w, A[3]);
      A[0] = fmaf(x.w, w3.x, A[0]); A[1] = fmaf(x.w, w3.y, A[1]);
      A[2] = fmaf(x.w, w3.z, A[2]); A[3] = fmaf(x.w, w3.w, A[3]);
    }
  }
  float s0 = 0.f, d0 = 0.f, s1 = 0.f, d1 = 0.f;
#pragma unroll
  for (int c = 0; c < 16; c++) {
    s0 = fmaf(acc[c], Asl[c], s0);
    d0 = fmaf(acc[c], Adl[c], d0);
    s1 = fmaf(acc[16 + c], Asl[16 + c], s1);
    d1 = fmaf(acc[16 + c], Adl[16 + c], d1);
  }
  as1[n * 2] = s0; as1[n * 2 + 1] = s1;
  ad1[n * 2] = d0; ad1[n * 2 + 1] = d1;
#pragma unroll
  for (int j = 0; j < 4; j++) {
    uint4 u;
    u.x = (unsigned)f2h(acc[j * 8 + 0]) | ((unsigned)f2h(acc[j * 8 + 1]) << 16);
    u.y = (unsigned)f2h(acc[j * 8 + 2]) | ((unsigned)f2h(acc[j * 8 + 3]) << 16);
    u.z = (unsigned)f2h(acc[j * 8 + 4]) | ((unsigned)f2h(acc[j * 8 + 5]) << 16);
    u.w = (unsigned)f2h(acc[j * 8 + 6]) | ((unsigned)f2h(acc[j * 8 + 7]) << 16);
    h1h[(size_t)n * 4 + j] = u;
  }
}

// ---------------- fused GEMM + attn + fp16 pack, layer 2 ----------------
// thread = node; h2 row (40ch) in regs; writes h2h (fp16, padded 128B row)
__global__ __launch_bounds__(256) void gemm2f(const float* __restrict__ X,
                                              const float* __restrict__ W,
                                              const float* __restrict__ att_s,
                                              const float* __restrict__ att_d,
                                              uint4* __restrict__ h2h,
                                              float* __restrict__ as2,
                                              float* __restrict__ ad2, int N) {
  __shared__ float Wl[32 * 40];
  __shared__ float Asl[40], Adl[40];
  int t = threadIdx.x;
  for (int i = t; i < 320; i += 256)
    ((float4*)Wl)[i] = ((const float4*)W)[i];
  if (t < 40) { Asl[t] = att_s[t]; Adl[t] = att_d[t]; }
  __syncthreads();
  int n = blockIdx.x * 256 + t;
  if (n >= N) return;
  const float4* X4 = (const float4*)(X + (size_t)n * 32);
  float acc[40];
#pragma unroll
  for (int c = 0; c < 40; c++) acc[c] = 0.f;
  for (int k4 = 0; k4 < 8; k4++) {
    float4 x = X4[k4];
    const float4* w4 = (const float4*)(Wl + k4 * 160);
#pragma unroll
    for (int c4 = 0; c4 < 10; c4++) {
      float4 w0 = w4[c4], w1 = w4[10 + c4], w2 = w4[20 + c4], w3 = w4[30 + c4];
      float* A = acc + c4 * 4;
      A[0] = fmaf(x.x, w0.x, A[0]); A[1] = fmaf(x.x, w0.y, A[1]);
      A[2] = fmaf(x.x, w0.z, A[2]); A[3] = fmaf(x.x, w0.w, A[3]);
      A[0] = fmaf(x.y, w1.x, A[0]); A[1] = fmaf(x.y, w1.y, A[1]);
      A[2] = fmaf(x.y, w1.z, A[2]); A[3] = fmaf(x.y, w1.w, A[3]);
      A[0] = fmaf(x.z, w2.x, A[0]); A[1] = fmaf(x.z, w2.y, A[1]);
      A[2] = fmaf(x.z, w2.z, A[2]); A[3] = fmaf(x.z, w2.w, A[3]);
      A[0] = fmaf(x.w, w3.x, A[0]); A[1] = fmaf(x.w, w3.y, A[1]);
      A[2] = fmaf(x.w, w3.z, A[2]); A[3] = fmaf(x.w, w3.w, A[3]);
    }
  }
  float ss = 0.f, sd = 0.f;
#pragma unroll
  for (int c = 0; c < 40; c++) {
    ss = fmaf(acc[c], Asl[c], ss);
    sd = fmaf(acc[c], Adl[c], sd);
  }
  as2[n] = ss; ad2[n] = sd;
#pragma unroll
  for (int j = 0; j < 5; j++) {
    uint4 u;
    u.x = (unsigned)f2h(acc[j * 8 + 0]) | ((unsigned)f2h(acc[j * 8 + 1]) << 16);
    u.y = (unsigned)f2h(acc[j * 8 + 2]) | ((unsigned)f2h(acc[j * 8 + 3]) << 16);
    u.z = (unsigned)f2h(acc[j * 8 + 4]) | ((unsigned)f2h(acc[j * 8 + 5]) << 16);
    u.w = (unsigned)f2h(acc[j * 8 + 6]) | ((unsigned)f2h(acc[j * 8 + 7]) << 16);
    h2h[(size_t)n * 8 + j] = u;  // 128B row stride, 80B used
  }
}

// ---------------- fused softmax+agg, layer 1 (fp16 payload, 64B row) --------
// thread = (node, 8 channels); head = cq>>1
__global__ __launch_bounds__(256) void agg1_fused(const int* __restrict__ rp,
                                                  const int* __restrict__ csr,
                                                  const float* __restrict__ as,
                                                  const float* __restrict__ ad,
                                                  const uint4* __restrict__ h1h,
                                                  const float* __restrict__ bias,
                                                  float* __restrict__ x1, int N) {
  int idx = blockIdx.x * 256 + threadIdx.x;  // over N*4
  if (idx >= N * 4) return;
  int n = idx >> 2, cq = idx & 3;
  int h = cq >> 1;
  int p0 = rp[n], p1 = rp[n + 1];
  float adv = ad[n * 2 + h];
  float acc[8] = {0, 0, 0, 0, 0, 0, 0, 0};
  float ssum = 0.f;
  for (int p = p0; p < p1; p++) {
    int s = csr[p];
    float e = as[s * 2 + h] + adv;
    e = e > 0.f ? e : 0.2f * e;
    float ex = __expf(e);
    ssum += ex;
    uint4 u = h1h[(size_t)s * 4 + cq];
    acc[0] = fmaf(ex, h2f(u.x & 0xffff), acc[0]);
    acc[1] = fmaf(ex, h2f(u.x >> 16),    acc[1]);
    acc[2] = fmaf(ex, h2f(u.y & 0xffff), acc[2]);
    acc[3] = fmaf(ex, h2f(u.y >> 16),    acc[3]);
    acc[4] = fmaf(ex, h2f(u.z & 0xffff), acc[4]);
    acc[5] = fmaf(ex, h2f(u.z >> 16),    acc[5]);
    acc[6] = fmaf(ex, h2f(u.w & 0xffff), acc[6]);
    acc[7] = fmaf(ex, h2f(u.w >> 16),    acc[7]);
  }
  float inv = 1.0f / (ssum + 1e-16f);
  const float4* b4 = (const float4*)bias;
  float4 ba = b4[cq * 2], bb = b4[cq * 2 + 1];
  float4 r0, r1;
  r0.x = fmaxf(fmaf(acc[0], inv, ba.x), 0.f);
  r0.y = fmaxf(fmaf(acc[1], inv, ba.y), 0.f);
  r0.z = fmaxf(fmaf(acc[2], inv, ba.z), 0.f);
  r0.w = fmaxf(fmaf(acc[3], inv, ba.w), 0.f);
  r1.x = fmaxf(fmaf(acc[4], inv, bb.x), 0.f);
  r1.y = fmaxf(fmaf(acc[5], inv, bb.y), 0.f);
  r1.z = fmaxf(fmaf(acc[6], inv, bb.z), 0.f);
  r1.w = fmaxf(fmaf(acc[7], inv, bb.w), 0.f);
  ((float4*)x1)[idx * 2]     = r0;
  ((float4*)x1)[idx * 2 + 1] = r1;
}

// ---------------- fused softmax+agg, layer 2 (fp16 padded payload) ----------
// thread = (node, 8 channels); 5 threads per node
__global__ __launch_bounds__(256) void agg2_fused(const int* __restrict__ rp,
                                                  const int* __restrict__ csr,
                                                  const float* __restrict__ as,
                                                  const float* __restrict__ ad,
                                                  const uint4* __restrict__ h2h,
                                                  const float* __restrict__ bias,
                                                  float* __restrict__ outp, int N) {
  int idx = blockIdx.x * 256 + threadIdx.x;  // over N*5
  if (idx >= N * 5) return;
  int n = idx / 5, cq = idx % 5;
  int p0 = rp[n], p1 = rp[n + 1];
  float adv = ad[n];
  float acc[8] = {0, 0, 0, 0, 0, 0, 0, 0};
  float ssum = 0.f;
  for (int p = p0; p < p1; p++) {
    int s = csr[p];
    float e = as[s] + adv;
    e = e > 0.f ? e : 0.2f * e;
    float ex = __expf(e);
    ssum += ex;
    uint4 u = h2h[(size_t)s * 8 + cq];
    acc[0] = fmaf(ex, h2f(u.x & 0xffff), acc[0]);
    acc[1] = fmaf(ex, h2f(u.x >> 16),    acc[1]);
    acc[2] = fmaf(ex, h2f(u.y & 0xffff), acc[2]);
    acc[3] = fmaf(ex, h2f(u.y >> 16),    acc[3]);
    acc[4] = fmaf(ex, h2f(u.z & 0xffff), acc[4]);
    acc[5] = fmaf(ex, h2f(u.z >> 16),    acc[5]);
    acc[6] = fmaf(ex, h2f(u.w & 0xffff), acc[6]);
    acc[7] = fmaf(ex, h2f(u.w >> 16),    acc[7]);
  }
  float inv = 1.0f / (ssum + 1e-16f);
  const float4* b4 = (const float4*)bias;
  float4 ba = b4[cq * 2], bb = b4[cq * 2 + 1];
  float4 r0, r1;
  r0.x = fmaf(acc[0], inv, ba.x);
  r0.y = fmaf(acc[1], inv, ba.y);
  r0.z = fmaf(acc[2], inv, ba.z);
  r0.w = fmaf(acc[3], inv, ba.w);
  r1.x = fmaf(acc[4], inv, bb.x);
  r1.y = fmaf(acc[5], inv, bb.y);
  r1.z = fmaf(acc[6], inv, bb.z);
  r1.w = fmaf(acc[7], inv, bb.w);
  ((float4*)outp)[idx * 2]     = r0;
  ((float4*)outp)[idx * 2 + 1] = r1;
}

// ---------------- host launcher ----------------
extern "C" void kernel_launch(void* const* d_in, const int* in_sizes, int n_in,
                              void* d_out, int out_size, void* d_ws, size_t ws_size,
                              hipStream_t stream) {
  const float* X    = (const float*)d_in[0];
  const long long* eg64 = (const long long*)d_in[1];
  const int* eg32   = (const int*)d_in[1];
  const float* W1   = (const float*)d_in[3];
  const float* as1w = (const float*)d_in[4];
  const float* ad1w = (const float*)d_in[5];
  const float* b1   = (const float*)d_in[6];
  const float* W2   = (const float*)d_in[7];
  const float* as2w = (const float*)d_in[8];
  const float* ad2w = (const float*)d_in[9];
  const float* b2   = (const float*)d_in[10];
  float* out = (float*)d_out;

  const int N  = in_sizes[0] / 128;
  const int E  = in_sizes[1] / 2;
  const int EN = E + N;
  const int NB2 = (N + CB_SZ - 1) / CB_SZ;
  const int NWG = (EN + CHUNK - 1) / CHUNK;
  const int NH  = NB2 * NWG;

  char* wbase = (char*)d_ws;
  size_t off = 0;
  auto alloc = [&](size_t bytes) -> void* {
    void* p = wbase + off;
    off += (bytes + 255) & ~(size_t)255;
    return p;
  };

  uint4* h1h = (uint4*)alloc((size_t)N * 64);        // fp16 h1, 64B rows
  uint4* h2h = (uint4*)alloc((size_t)N * 128);       // fp16 h2, 128B padded rows
  float* x1  = (float*)alloc((size_t)N * 32 * 4);
  float* as1 = (float*)alloc((size_t)N * 2 * 4);
  float* ad1 = (float*)alloc((size_t)N * 2 * 4);
  float* as2 = (float*)alloc((size_t)N * 4);
  float* ad2 = (float*)alloc((size_t)N * 4);
  int* rp     = (int*)alloc((size_t)(N + 1) * 4);
  int* histg  = (int*)alloc((size_t)NH * 4);
  int* hists  = (int*)alloc((size_t)(NH + 1) * 4);
  int* bsum   = (int*)alloc(1024 * 4);
  int* boff   = (int*)alloc(1024 * 4);
  int* flag   = (int*)alloc(256);
  int* csr    = (int*)alloc((size_t)EN * 4);
  int* tmp    = (int*)alloc((size_t)EN * 4);
  (void)ws_size; (void)n_in; (void)out_size;

  const int gN  = (N + 255) / 256;
  const int nbH = (NH + 1023) / 1024;

  detect_kernel<<<1, 256, 0, stream>>>(eg32, E, flag);

  // CSR build (atomic-free)
  chunk_hist<<<NWG, 256, 0, stream>>>(eg64, eg32, flag, E, N, NWG, histg);
  scan_blocks<<<nbH, 1024, 0, stream>>>(histg, hists, bsum, NH);
  scan_sums<<<1, 64, 0, stream>>>(bsum, boff, nbH);
  scan_add<<<nbH, 1024, 0, stream>>>(hists, boff, NH, EN);
  chunk_scatter<<<NWG, 256, 0, stream>>>(eg64, eg32, flag, E, N, NWG, hists, tmp);
  bucket_rp<<<NB2, 256, 0, stream>>>(hists, NWG, tmp, rp, N, EN);
  bucket_sort<<<NB2, 256, 0, stream>>>(rp, tmp, csr, N);

  // Layer 1
  gemm1f<<<gN, 256, 0, stream>>>(X, W1, as1w, ad1w, h1h, as1, ad1, N);
  agg1_fused<<<(N * 4 + 255) / 256, 256, 0, stream>>>(rp, csr, as1, ad1, h1h, b1, x1, N);

  // Layer 2
  gemm2f<<<gN, 256, 0, stream>>>(x1, W2, as2w, ad2w, h2h, as2, ad2, N);
  agg2_fused<<<(N * 5 + 255) / 256, 256, 0, stream>>>(rp, csr, as2, ad2, h2h, b2, out, N);
}

// Round 6
// 392.268 us; speedup vs baseline: 3.8600x; 1.1545x over previous
//
#include <hip/hip_runtime.h>

// GAT 2-layer forward on MI355X.
// Round 6: aggregation is latency-bound (r5: occupancy 54%, 2.9TB/s eff, VALU 15%)
//  - split-K aggs: 2 threads per (node,chunk) take interleaved edge halves;
//    agg1 combines via shfl_xor(4) (8 thr/node, wave-aligned), agg2 via LDS
//    (10 thr/node, 250-thread blocks so nodes never straddle).
//  - 2x manual unroll of gather loops (independent load pairs -> deeper MLP).
//  - bucket_rp + bucket_sort merged (cursors already in LDS post-scan).
// Payloads: h1h fp16 64B rows, h2h fp16 128B-padded rows (r5: 1 line/edge).

#define DEVFN __device__ __forceinline__
#define CB_SHIFT 9
#define CB_SZ 512
#define CHUNK 8192
#define A2B 250  // agg2 active threads per block (multiple of 10)

DEVFN unsigned short f2h(float f) {
  _Float16 h = (_Float16)f;
  unsigned short u;
  __builtin_memcpy(&u, &h, 2);
  return u;
}
DEVFN float h2f(unsigned short u) {
  _Float16 h;
  __builtin_memcpy(&h, &u, 2);
  return (float)h;
}

// ---------------- edge dtype detection (int64 vs int32) ----------------
__global__ void detect_kernel(const int* eg32, int E, int* flag) {
  __shared__ int any;
  if (threadIdx.x == 0) any = 0;
  __syncthreads();
  for (int k = threadIdx.x; k < 2048 && k < E; k += 256) {
    if (eg32[2 * k + 1] != 0) atomicOr(&any, 1);
  }
  __syncthreads();
  if (threadIdx.x == 0) flag[0] = any ? 0 : 1;  // 1 => int64
}

DEVFN int read_dst(const long long* eg64, const int* eg32, int is64, int E, int i) {
  if (i >= E) return i - E;
  return is64 ? (int)eg64[E + i] : eg32[E + i];
}

DEVFN void read_edge(const long long* eg64, const int* eg32, int is64, int E,
                     int i, int& s, int& d) {
  if (i >= E) { s = d = i - E; return; }
  if (is64) { s = (int)eg64[i]; d = (int)eg64[E + i]; }
  else      { s = eg32[i];      d = eg32[E + i]; }
}

// ---------------- generic scan (blocks of 1024) for chunk histograms --------
__global__ void scan_blocks(const int* __restrict__ cnt, int* __restrict__ rp,
                            int* __restrict__ bsum, int n) {
  __shared__ int buf[2][1024];
  int t = threadIdx.x;
  int gid = blockIdx.x * 1024 + t;
  int v = (gid < n) ? cnt[gid] : 0;
  buf[0][t] = v;
  __syncthreads();
  int pin = 0;
  for (int offd = 1; offd < 1024; offd <<= 1) {
    int nv = buf[pin][t];
    if (t >= offd) nv += buf[pin][t - offd];
    buf[1 - pin][t] = nv;
    pin = 1 - pin;
    __syncthreads();
  }
  int inc = buf[pin][t];
  if (gid < n) rp[gid] = inc - v;  // exclusive within block
  if (t == 1023) bsum[blockIdx.x] = inc;
}

__global__ void scan_sums(const int* bsum, int* boff, int nb) {
  if (blockIdx.x == 0 && threadIdx.x == 0) {
    int r = 0;
    for (int i = 0; i < nb; i++) { boff[i] = r; r += bsum[i]; }
  }
}

__global__ void scan_add(int* rp, const int* boff, int n, int total) {
  int i = blockIdx.x * 1024 + threadIdx.x;
  if (i < n) rp[i] = rp[i] + boff[blockIdx.x];
  if (i == 0) rp[n] = total;
}

// ---------------- CSR build (atomic-free multisplit) ----------------
__global__ __launch_bounds__(256) void chunk_hist(const long long* eg64,
                                                  const int* eg32, const int* flag,
                                                  int E, int N, int NWG,
                                                  int* __restrict__ histg) {
  __shared__ int lh[CB_SZ];
  int w = blockIdx.x, t = threadIdx.x;
  int NB2 = (N + CB_SZ - 1) / CB_SZ;
  for (int j = t; j < NB2; j += 256) lh[j] = 0;
  __syncthreads();
  int is64 = flag[0];
  int EN = E + N;
  int i0 = w * CHUNK;
  int i1 = i0 + CHUNK; if (i1 > EN) i1 = EN;
  for (int i = i0 + t; i < i1; i += 256) {
    int d = read_dst(eg64, eg32, is64, E, i);
    atomicAdd(&lh[d >> CB_SHIFT], 1);
  }
  __syncthreads();
  for (int b = t; b < NB2; b += 256) histg[b * NWG + w] = lh[b];
}

__global__ __launch_bounds__(256) void chunk_scatter(const long long* eg64,
                                                     const int* eg32, const int* flag,
                                                     int E, int N, int NWG,
                                                     const int* __restrict__ hists,
                                                     int* __restrict__ tmp) {
  __shared__ int lcur[CB_SZ];
  int w = blockIdx.x, t = threadIdx.x;
  int NB2 = (N + CB_SZ - 1) / CB_SZ;
  for (int b = t; b < NB2; b += 256) lcur[b] = hists[b * NWG + w];
  __syncthreads();
  int is64 = flag[0];
  int EN = E + N;
  int i0 = w * CHUNK;
  int i1 = i0 + CHUNK; if (i1 > EN) i1 = EN;
  for (int i = i0 + t; i < i1; i += 256) {
    int s, d;
    read_edge(eg64, eg32, is64, E, i, s, d);
    int b = d >> CB_SHIFT;
    int pos = atomicAdd(&lcur[b], 1);
    tmp[pos] = (s << CB_SHIFT) | (d & (CB_SZ - 1));
  }
}

// per-bucket: node counts + in-LDS scan -> rp; then scatter tmp -> csr using
// the same LDS cursors (merged bucket_rp + bucket_sort)
__global__ __launch_bounds__(256) void bucket_rp_sort(const int* __restrict__ hists,
                                                      int NWG,
                                                      const int* __restrict__ tmp,
                                                      int* __restrict__ rp,
                                                      int* __restrict__ csr,
                                                      int N, int EN) {
  __shared__ int lc[CB_SZ];
  __shared__ int ps[256];
  __shared__ int lcur[CB_SZ];
  int b = blockIdx.x, t = threadIdx.x;
  for (int j = t; j < CB_SZ; j += 256) lc[j] = 0;
  __syncthreads();
  int w0 = hists[b * NWG];
  int w1 = hists[(b + 1) * NWG];  // last bucket reads hists[NB2*NWG] == EN
  for (int p = w0 + t; p < w1; p += 256)
    atomicAdd(&lc[tmp[p] & (CB_SZ - 1)], 1);
  __syncthreads();
  int a = lc[2 * t], c = lc[2 * t + 1];
  ps[t] = a + c;
  __syncthreads();
  for (int off = 1; off < 256; off <<= 1) {
    int v = ps[t];
    int u = (t >= off) ? ps[t - off] : 0;
    __syncthreads();
    ps[t] = v + u;
    __syncthreads();
  }
  int base = w0 + ps[t] - (a + c);  // exclusive prefix within bucket
  lcur[2 * t] = base;
  lcur[2 * t + 1] = base + a;
  int n0 = b * CB_SZ;
  if (n0 + 2 * t < N) rp[n0 + 2 * t] = base;
  if (n0 + 2 * t + 1 < N) rp[n0 + 2 * t + 1] = base + a;
  if (b == (int)gridDim.x - 1 && t == 0) rp[N] = EN;
  __syncthreads();
  for (int p = w0 + t; p < w1; p += 256) {
    int e = tmp[p];
    int dl = e & (CB_SZ - 1);
    int s = e >> CB_SHIFT;
    int pos = atomicAdd(&lcur[dl], 1);
    csr[pos] = s;
  }
}

// ---------------- fused GEMM + attn + fp16 pack, layer 1 ----------------
__global__ __launch_bounds__(256) void gemm1f(const float* __restrict__ X,
                                              const float* __restrict__ W,
                                              const float* __restrict__ att_s,
                                              const float* __restrict__ att_d,
                                              uint4* __restrict__ h1h,
                                              float* __restrict__ as1,
                                              float* __restrict__ ad1, int N) {
  __shared__ float Wl[128 * 32];
  __shared__ float Asl[32], Adl[32];
  int t = threadIdx.x;
  for (int i = t; i < 1024; i += 256)
    ((float4*)Wl)[i] = ((const float4*)W)[i];
  if (t < 32) { Asl[t] = att_s[t]; Adl[t] = att_d[t]; }
  __syncthreads();
  int n = blockIdx.x * 256 + t;
  if (n >= N) return;
  const float4* X4 = (const float4*)(X + (size_t)n * 128);
  float acc[32];
#pragma unroll
  for (int c = 0; c < 32; c++) acc[c] = 0.f;
  for (int k4 = 0; k4 < 32; k4++) {
    float4 x = X4[k4];
    const float4* w4 = (const float4*)(Wl + k4 * 128);
#pragma unroll
    for (int c4 = 0; c4 < 8; c4++) {
      float4 w0 = w4[c4], w1 = w4[8 + c4], w2 = w4[16 + c4], w3 = w4[24 + c4];
      float* A = acc + c4 * 4;
      A[0] = fmaf(x.x, w0.x, A[0]); A[1] = fmaf(x.x, w0.y, A[1]);
      A[2] = fmaf(x.x, w0.z, A[2]); A[3] = fmaf(x.x, w0.w, A[3]);
      A[0] = fmaf(x.y, w1.x, A[0]); A[1] = fmaf(x.y, w1.y, A[1]);
      A[2] = fmaf(x.y, w1.z, A[2]); A[3] = fmaf(x.y, w1.w, A[3]);
      A[0] = fmaf(x.z, w2.x, A[0]); A[1] = fmaf(x.z, w2.y, A[1]);
      A[2] = fmaf(x.z, w2.z, A[2]); A[3] = fmaf(x.z, w2.w, A[3]);
      A[0] = fmaf(x.w, w3.x, A[0]); A[1] = fmaf(x.w, w3.y, A[1]);
      A[2] = fmaf(x.w, w3.z, A[2]); A[3] = fmaf(x.w, w3.w, A[3]);
    }
  }
  float s0 = 0.f, d0 = 0.f, s1 = 0.f, d1 = 0.f;
#pragma unroll
  for (int c = 0; c < 16; c++) {
    s0 = fmaf(acc[c], Asl[c], s0);
    d0 = fmaf(acc[c], Adl[c], d0);
    s1 = fmaf(acc[16 + c], Asl[16 + c], s1);
    d1 = fmaf(acc[16 + c], Adl[16 + c], d1);
  }
  as1[n * 2] = s0; as1[n * 2 + 1] = s1;
  ad1[n * 2] = d0; ad1[n * 2 + 1] = d1;
#pragma unroll
  for (int j = 0; j < 4; j++) {
    uint4 u;
    u.x = (unsigned)f2h(acc[j * 8 + 0]) | ((unsigned)f2h(acc[j * 8 + 1]) << 16);
    u.y = (unsigned)f2h(acc[j * 8 + 2]) | ((unsigned)f2h(acc[j * 8 + 3]) << 16);
    u.z = (unsigned)f2h(acc[j * 8 + 4]) | ((unsigned)f2h(acc[j * 8 + 5]) << 16);
    u.w = (unsigned)f2h(acc[j * 8 + 6]) | ((unsigned)f2h(acc[j * 8 + 7]) << 16);
    h1h[(size_t)n * 4 + j] = u;
  }
}

// ---------------- fused GEMM + attn + fp16 pack, layer 2 ----------------
__global__ __launch_bounds__(256) void gemm2f(const float* __restrict__ X,
                                              const float* __restrict__ W,
                                              const float* __restrict__ att_s,
                                              const float* __restrict__ att_d,
                                              uint4* __restrict__ h2h,
                                              float* __restrict__ as2,
                                              float* __restrict__ ad2, int N) {
  __shared__ float Wl[32 * 40];
  __shared__ float Asl[40], Adl[40];
  int t = threadIdx.x;
  for (int i = t; i < 320; i += 256)
    ((float4*)Wl)[i] = ((const float4*)W)[i];
  if (t < 40) { Asl[t] = att_s[t]; Adl[t] = att_d[t]; }
  __syncthreads();
  int n = blockIdx.x * 256 + t;
  if (n >= N) return;
  const float4* X4 = (const float4*)(X + (size_t)n * 32);
  float acc[40];
#pragma unroll
  for (int c = 0; c < 40; c++) acc[c] = 0.f;
  for (int k4 = 0; k4 < 8; k4++) {
    float4 x = X4[k4];
    const float4* w4 = (const float4*)(Wl + k4 * 160);
#pragma unroll
    for (int c4 = 0; c4 < 10; c4++) {
      float4 w0 = w4[c4], w1 = w4[10 + c4], w2 = w4[20 + c4], w3 = w4[30 + c4];
      float* A = acc + c4 * 4;
      A[0] = fmaf(x.x, w0.x, A[0]); A[1] = fmaf(x.x, w0.y, A[1]);
      A[2] = fmaf(x.x, w0.z, A[2]); A[3] = fmaf(x.x, w0.w, A[3]);
      A[0] = fmaf(x.y, w1.x, A[0]); A[1] = fmaf(x.y, w1.y, A[1]);
      A[2] = fmaf(x.y, w1.z, A[2]); A[3] = fmaf(x.y, w1.w, A[3]);
      A[0] = fmaf(x.z, w2.x, A[0]); A[1] = fmaf(x.z, w2.y, A[1]);
      A[2] = fmaf(x.z, w2.z, A[2]); A[3] = fmaf(x.z, w2.w, A[3]);
      A[0] = fmaf(x.w, w3.x, A[0]); A[1] = fmaf(x.w, w3.y, A[1]);
      A[2] = fmaf(x.w, w3.z, A[2]); A[3] = fmaf(x.w, w3.w, A[3]);
    }
  }
  float ss = 0.f, sd = 0.f;
#pragma unroll
  for (int c = 0; c < 40; c++) {
    ss = fmaf(acc[c], Asl[c], ss);
    sd = fmaf(acc[c], Adl[c], sd);
  }
  as2[n] = ss; ad2[n] = sd;
#pragma unroll
  for (int j = 0; j < 5; j++) {
    uint4 u;
    u.x = (unsigned)f2h(acc[j * 8 + 0]) | ((unsigned)f2h(acc[j * 8 + 1]) << 16);
    u.y = (unsigned)f2h(acc[j * 8 + 2]) | ((unsigned)f2h(acc[j * 8 + 3]) << 16);
    u.z = (unsigned)f2h(acc[j * 8 + 4]) | ((unsigned)f2h(acc[j * 8 + 5]) << 16);
    u.w = (unsigned)f2h(acc[j * 8 + 6]) | ((unsigned)f2h(acc[j * 8 + 7]) << 16);
    h2h[(size_t)n * 8 + j] = u;  // 128B row stride, 80B used
  }
}

// ---------------- fused softmax+agg, layer 1 (split-K, shfl combine) --------
// idx over N*8: n=idx>>3, half=(idx>>2)&1, cq=idx&3 (16B chunk of 64B row)
__global__ __launch_bounds__(256) void agg1_fused(const int* __restrict__ rp,
                                                  const int* __restrict__ csr,
                                                  const float* __restrict__ as,
                                                  const float* __restrict__ ad,
                                                  const uint4* __restrict__ h1h,
                                                  const float* __restrict__ bias,
                                                  float* __restrict__ x1, int N) {
  int idx = blockIdx.x * 256 + threadIdx.x;
  if (idx >= N * 8) return;
  int n = idx >> 3;
  int half = (idx >> 2) & 1;
  int cq = idx & 3;
  int h = cq >> 1;
  int p0 = rp[n], p1 = rp[n + 1];
  float adv = ad[n * 2 + h];
  float acc[8] = {0, 0, 0, 0, 0, 0, 0, 0};
  float ssum = 0.f;
  int p = p0 + half;
  for (; p + 2 < p1; p += 4) {
    int s0 = csr[p], s1 = csr[p + 2];
    float e0 = as[s0 * 2 + h] + adv;
    float e1 = as[s1 * 2 + h] + adv;
    uint4 u0 = h1h[(size_t)s0 * 4 + cq];
    uint4 u1 = h1h[(size_t)s1 * 4 + cq];
    e0 = e0 > 0.f ? e0 : 0.2f * e0;
    e1 = e1 > 0.f ? e1 : 0.2f * e1;
    float x0 = __expf(e0), x1e = __expf(e1);
    ssum += x0 + x1e;
    acc[0] = fmaf(x0, h2f(u0.x & 0xffff), acc[0]);
    acc[1] = fmaf(x0, h2f(u0.x >> 16),    acc[1]);
    acc[2] = fmaf(x0, h2f(u0.y & 0xffff), acc[2]);
    acc[3] = fmaf(x0, h2f(u0.y >> 16),    acc[3]);
    acc[4] = fmaf(x0, h2f(u0.z & 0xffff), acc[4]);
    acc[5] = fmaf(x0, h2f(u0.z >> 16),    acc[5]);
    acc[6] = fmaf(x0, h2f(u0.w & 0xffff), acc[6]);
    acc[7] = fmaf(x0, h2f(u0.w >> 16),    acc[7]);
    acc[0] = fmaf(x1e, h2f(u1.x & 0xffff), acc[0]);
    acc[1] = fmaf(x1e, h2f(u1.x >> 16),    acc[1]);
    acc[2] = fmaf(x1e, h2f(u1.y & 0xffff), acc[2]);
    acc[3] = fmaf(x1e, h2f(u1.y >> 16),    acc[3]);
    acc[4] = fmaf(x1e, h2f(u1.z & 0xffff), acc[4]);
    acc[5] = fmaf(x1e, h2f(u1.z >> 16),    acc[5]);
    acc[6] = fmaf(x1e, h2f(u1.w & 0xffff), acc[6]);
    acc[7] = fmaf(x1e, h2f(u1.w >> 16),    acc[7]);
  }
  for (; p < p1; p += 2) {
    int s = csr[p];
    float e = as[s * 2 + h] + adv;
    uint4 u = h1h[(size_t)s * 4 + cq];
    e = e > 0.f ? e : 0.2f * e;
    float ex = __expf(e);
    ssum += ex;
    acc[0] = fmaf(ex, h2f(u.x & 0xffff), acc[0]);
    acc[1] = fmaf(ex, h2f(u.x >> 16),    acc[1]);
    acc[2] = fmaf(ex, h2f(u.y & 0xffff), acc[2]);
    acc[3] = fmaf(ex, h2f(u.y >> 16),    acc[3]);
    acc[4] = fmaf(ex, h2f(u.z & 0xffff), acc[4]);
    acc[5] = fmaf(ex, h2f(u.z >> 16),    acc[5]);
    acc[6] = fmaf(ex, h2f(u.w & 0xffff), acc[6]);
    acc[7] = fmaf(ex, h2f(u.w >> 16),    acc[7]);
  }
  // combine halves (partner lane = idx^4, same wave: 8 threads per node)
#pragma unroll
  for (int j = 0; j < 8; j++) acc[j] += __shfl_xor(acc[j], 4);
  ssum += __shfl_xor(ssum, 4);
  float inv = 1.0f / (ssum + 1e-16f);
  float4 bv = ((const float4*)bias)[cq * 2 + half];
  const float* A = acc + half * 4;
  float4 r;
  r.x = fmaxf(fmaf(A[0], inv, bv.x), 0.f);
  r.y = fmaxf(fmaf(A[1], inv, bv.y), 0.f);
  r.z = fmaxf(fmaf(A[2], inv, bv.z), 0.f);
  r.w = fmaxf(fmaf(A[3], inv, bv.w), 0.f);
  ((float4*)x1)[(size_t)n * 8 + cq * 2 + half] = r;
}

// ---------------- fused softmax+agg, layer 2 (split-K, LDS combine) ---------
// blocks of 250 active threads (25 nodes x 10); r = half*5 + cq
__global__ __launch_bounds__(256) void agg2_fused(const int* __restrict__ rp,
                                                  const int* __restrict__ csr,
                                                  const float* __restrict__ as,
                                                  const float* __restrict__ ad,
                                                  const uint4* __restrict__ h2h,
                                                  const float* __restrict__ bias,
                                                  float* __restrict__ outp, int N) {
  __shared__ float part[256][9];
  int t = threadIdx.x;
  int idx = blockIdx.x * A2B + t;
  bool act = (t < A2B) && (idx < N * 10);
  int n = 0, half = 0, cq = 0, p0 = 0, p1 = 0;
  float adv = 0.f;
  if (act) {
    n = idx / 10;
    int r = idx % 10;
    half = r >= 5;
    cq = r - half * 5;
    p0 = rp[n]; p1 = rp[n + 1];
    adv = ad[n];
  }
  float acc[8] = {0, 0, 0, 0, 0, 0, 0, 0};
  float ssum = 0.f;
  if (act) {
    int p = p0 + half;
    for (; p + 2 < p1; p += 4) {
      int s0 = csr[p], s1 = csr[p + 2];
      float e0 = as[s0] + adv;
      float e1 = as[s1] + adv;
      uint4 u0 = h2h[(size_t)s0 * 8 + cq];
      uint4 u1 = h2h[(size_t)s1 * 8 + cq];
      e0 = e0 > 0.f ? e0 : 0.2f * e0;
      e1 = e1 > 0.f ? e1 : 0.2f * e1;
      float x0 = __expf(e0), x1e = __expf(e1);
      ssum += x0 + x1e;
      acc[0] = fmaf(x0, h2f(u0.x & 0xffff), acc[0]);
      acc[1] = fmaf(x0, h2f(u0.x >> 16),    acc[1]);
      acc[2] = fmaf(x0, h2f(u0.y & 0xffff), acc[2]);
      acc[3] = fmaf(x0, h2f(u0.y >> 16),    acc[3]);
      acc[4] = fmaf(x0, h2f(u0.z & 0xffff), acc[4]);
      acc[5] = fmaf(x0, h2f(u0.z >> 16),    acc[5]);
      acc[6] = fmaf(x0, h2f(u0.w & 0xffff), acc[6]);
      acc[7] = fmaf(x0, h2f(u0.w >> 16),    acc[7]);
      acc[0] = fmaf(x1e, h2f(u1.x & 0xffff), acc[0]);
      acc[1] = fmaf(x1e, h2f(u1.x >> 16),    acc[1]);
      acc[2] = fmaf(x1e, h2f(u1.y & 0xffff), acc[2]);
      acc[3] = fmaf(x1e, h2f(u1.y >> 16),    acc[3]);
      acc[4] = fmaf(x1e, h2f(u1.z & 0xffff), acc[4]);
      acc[5] = fmaf(x1e, h2f(u1.z >> 16),    acc[5]);
      acc[6] = fmaf(x1e, h2f(u1.w & 0xffff), acc[6]);
      acc[7] = fmaf(x1e, h2f(u1.w >> 16),    acc[7]);
    }
    for (; p < p1; p += 2) {
      int s = csr[p];
      float e = as[s] + adv;
      uint4 u = h2h[(size_t)s * 8 + cq];
      e = e > 0.f ? e : 0.2f * e;
      float ex = __expf(e);
      ssum += ex;
      acc[0] = fmaf(ex, h2f(u.x & 0xffff), acc[0]);
      acc[1] = fmaf(ex, h2f(u.x >> 16),    acc[1]);
      acc[2] = fmaf(ex, h2f(u.y & 0xffff), acc[2]);
      acc[3] = fmaf(ex, h2f(u.y >> 16),    acc[3]);
      acc[4] = fmaf(ex, h2f(u.z & 0xffff), acc[4]);
      acc[5] = fmaf(ex, h2f(u.z >> 16),    acc[5]);
      acc[6] = fmaf(ex, h2f(u.w & 0xffff), acc[6]);
      acc[7] = fmaf(ex, h2f(u.w >> 16),    acc[7]);
    }
  }
  if (act && half) {
#pragma unroll
    for (int j = 0; j < 8; j++) part[t][j] = acc[j];
    part[t][8] = ssum;
  }
  __syncthreads();
  if (act && !half) {
#pragma unroll
    for (int j = 0; j < 8; j++) acc[j] += part[t + 5][j];
    ssum += part[t + 5][8];
    float inv = 1.0f / (ssum + 1e-16f);
    const float4* b4 = (const float4*)bias;
    float4 ba = b4[cq * 2], bb = b4[cq * 2 + 1];
    float4 r0, r1;
    r0.x = fmaf(acc[0], inv, ba.x);
    r0.y = fmaf(acc[1], inv, ba.y);
    r0.z = fmaf(acc[2], inv, ba.z);
    r0.w = fmaf(acc[3], inv, ba.w);
    r1.x = fmaf(acc[4], inv, bb.x);
    r1.y = fmaf(acc[5], inv, bb.y);
    r1.z = fmaf(acc[6], inv, bb.z);
    r1.w = fmaf(acc[7], inv, bb.w);
    ((float4*)outp)[(size_t)n * 10 + cq * 2]     = r0;
    ((float4*)outp)[(size_t)n * 10 + cq * 2 + 1] = r1;
  }
}

// ---------------- host launcher ----------------
extern "C" void kernel_launch(void* const* d_in, const int* in_sizes, int n_in,
                              void* d_out, int out_size, void* d_ws, size_t ws_size,
                              hipStream_t stream) {
  const float* X    = (const float*)d_in[0];
  const long long* eg64 = (const long long*)d_in[1];
  const int* eg32   = (const int*)d_in[1];
  const float* W1   = (const float*)d_in[3];
  const float* as1w = (const float*)d_in[4];
  const float* ad1w = (const float*)d_in[5];
  const float* b1   = (const float*)d_in[6];
  const float* W2   = (const float*)d_in[7];
  const float* as2w = (const float*)d_in[8];
  const float* ad2w = (const float*)d_in[9];
  const float* b2   = (const float*)d_in[10];
  float* out = (float*)d_out;

  const int N  = in_sizes[0] / 128;
  const int E  = in_sizes[1] / 2;
  const int EN = E + N;
  const int NB2 = (N + CB_SZ - 1) / CB_SZ;
  const int NWG = (EN + CHUNK - 1) / CHUNK;
  const int NH  = NB2 * NWG;

  char* wbase = (char*)d_ws;
  size_t off = 0;
  auto alloc = [&](size_t bytes) -> void* {
    void* p = wbase + off;
    off += (bytes + 255) & ~(size_t)255;
    return p;
  };

  uint4* h1h = (uint4*)alloc((size_t)N * 64);        // fp16 h1, 64B rows
  uint4* h2h = (uint4*)alloc((size_t)N * 128);       // fp16 h2, 128B padded rows
  float* x1  = (float*)alloc((size_t)N * 32 * 4);
  float* as1 = (float*)alloc((size_t)N * 2 * 4);
  float* ad1 = (float*)alloc((size_t)N * 2 * 4);
  float* as2 = (float*)alloc((size_t)N * 4);
  float* ad2 = (float*)alloc((size_t)N * 4);
  int* rp     = (int*)alloc((size_t)(N + 1) * 4);
  int* histg  = (int*)alloc((size_t)NH * 4);
  int* hists  = (int*)alloc((size_t)(NH + 1) * 4);
  int* bsum   = (int*)alloc(1024 * 4);
  int* boff   = (int*)alloc(1024 * 4);
  int* flag   = (int*)alloc(256);
  int* csr    = (int*)alloc((size_t)EN * 4);
  int* tmp    = (int*)alloc((size_t)EN * 4);
  (void)ws_size; (void)n_in; (void)out_size;

  const int gN  = (N + 255) / 256;
  const int nbH = (NH + 1023) / 1024;

  detect_kernel<<<1, 256, 0, stream>>>(eg32, E, flag);

  // CSR build (atomic-free)
  chunk_hist<<<NWG, 256, 0, stream>>>(eg64, eg32, flag, E, N, NWG, histg);
  scan_blocks<<<nbH, 1024, 0, stream>>>(histg, hists, bsum, NH);
  scan_sums<<<1, 64, 0, stream>>>(bsum, boff, nbH);
  scan_add<<<nbH, 1024, 0, stream>>>(hists, boff, NH, EN);
  chunk_scatter<<<NWG, 256, 0, stream>>>(eg64, eg32, flag, E, N, NWG, hists, tmp);
  bucket_rp_sort<<<NB2, 256, 0, stream>>>(hists, NWG, tmp, rp, csr, N, EN);

  // Layer 1
  gemm1f<<<gN, 256, 0, stream>>>(X, W1, as1w, ad1w, h1h, as1, ad1, N);
  agg1_fused<<<(N * 8 + 255) / 256, 256, 0, stream>>>(rp, csr, as1, ad1, h1h, b1, x1, N);

  // Layer 2
  gemm2f<<<gN, 256, 0, stream>>>(x1, W2, as2w, ad2w, h2h, as2, ad2, N);
  agg2_fused<<<(N * 10 + A2B - 1) / A2B, 256, 0, stream>>>(rp, csr, as2, ad2, h2h, b2, out, N);
}